// Round 6
// baseline (2009.117 us; speedup 1.0000x reference)
//
#include <hip/hip_runtime.h>
#include <hip/hip_bf16.h>
#include <math.h>

#define NN 50000
#define NE 800000
#define NEP (NE + NN)   /* edges + self loops */
#define NG 128

__device__ __forceinline__ float lrelu02(float v) {
  return fmaxf(v, 0.0f) + 0.2f * fminf(v, 0.0f);
}
__device__ __forceinline__ float eluf(float v) {
  return v > 0.0f ? v : expm1f(v);
}
__device__ __forceinline__ float bflo(unsigned u) {
  union { unsigned i; float f; } c; c.i = u << 16; return c.f;
}
__device__ __forceinline__ float bfhi(unsigned u) {
  union { unsigned i; float f; } c; c.i = u & 0xffff0000u; return c.f;
}

__global__ __launch_bounds__(256) void k_deg(const int* __restrict__ ei, int* __restrict__ deg) {
  int t = blockIdx.x * 256 + threadIdx.x;
  if (t >= NEP) return;
  int dst = (t < NE) ? ei[NE + t] : (t - NE);
  atomicAdd(&deg[dst], 1);
}

__global__ __launch_bounds__(1024) void k_scan(const int* __restrict__ deg, int* __restrict__ rowptr) {
  __shared__ int part[1024];
  int t = threadIdx.x;
  const int CH = (NN + 1023) >> 10;          // 49
  int b = t * CH;
  int e = min(b + CH, NN);
  int s = 0;
  for (int i = b; i < e; ++i) s += deg[i];
  part[t] = s;
  __syncthreads();
  for (int off = 1; off < 1024; off <<= 1) {
    int v = (t >= off) ? part[t - off] : 0;
    __syncthreads();
    part[t] += v;
    __syncthreads();
  }
  int run = (t == 0) ? 0 : part[t - 1];
  for (int i = b; i < e; ++i) { rowptr[i] = run; run += deg[i]; }
  if (t == 1023) rowptr[NN] = part[1023];
}

__global__ __launch_bounds__(256) void k_scatter(const int* __restrict__ ei, const int* __restrict__ rowptr,
                                                 int* __restrict__ fill, int* __restrict__ srcidx) {
  int t = blockIdx.x * 256 + threadIdx.x;
  if (t >= NEP) return;
  int src, dst;
  if (t < NE) { src = ei[t]; dst = ei[NE + t]; } else { src = t - NE; dst = src; }
  int pos = atomicAdd(&fill[dst], 1);
  srcidx[rowptr[dst] + pos] = src;
}

// ---- dual GEMM: Yl = X@Wl^T+bl (bf16 out), Yr = X@Wr^T+br (f32 out) ----
// X tile + both W tiles in LDS. W tiles padded to [..][65]: staging ds_write_b128
// becomes 2-way (free) instead of 16-way bank conflict (verified r5: conflicts->0).
// Inner loop: simple k-loop (NOT unrolled - r5 showed unroll => 256 VGPR + spill),
// fmaf chains. Block = 32 rows (4 waves x 8) x 64 cols.
template <int DIN>
__global__ __launch_bounds__(256) void k_gemm2(const float* __restrict__ X,
                                               const float* __restrict__ Wl, const float* __restrict__ bl,
                                               const float* __restrict__ Wr, const float* __restrict__ br,
                                               __hip_bfloat16* __restrict__ Yl, float* __restrict__ Yr,
                                               int dout) {
  constexpr int K4 = DIN / 4;
  constexpr int K4H = (K4 > 16) ? 16 : K4;   // stage W in K-halves when DIN=128
  constexpr int NST = K4 / K4H;
  __shared__ float4 xs[32][K4];
  __shared__ float4 wls[K4H][65];
  __shared__ float4 wrs[K4H][65];
  int t = threadIdx.x;
  int lane = t & 63;
  int wid = t >> 6;
  int row0 = blockIdx.x * 32;
  int col0 = blockIdx.y * 64;

  for (int s = t; s < 32 * K4; s += 256) {
    int r = s / K4, k4 = s % K4;
    int row = row0 + r;
    float4 v = {0.f, 0.f, 0.f, 0.f};
    if (row < NN) v = ((const float4*)(X + (size_t)row * DIN))[k4];
    xs[r][k4] = v;
  }

  float accl[8] = {};
  float accr[8] = {};
  for (int st = 0; st < NST; ++st) {
    __syncthreads();   // xs ready (st=0); previous stage's compute done (st>0)
    for (int s = t; s < 64 * K4H; s += 256) {
      int c = s / K4H, k = s % K4H;   // 16 consecutive lanes read one W row contiguously
      wls[k][c] = ((const float4*)(Wl + (size_t)(col0 + c) * DIN))[st * K4H + k];
      wrs[k][c] = ((const float4*)(Wr + (size_t)(col0 + c) * DIN))[st * K4H + k];
    }
    __syncthreads();
    for (int k = 0; k < K4H; ++k) {
      float4 w4l = wls[k][lane];
      float4 w4r = wrs[k][lane];
#pragma unroll
      for (int r = 0; r < 8; ++r) {
        float4 xv = xs[wid * 8 + r][st * K4H + k];
        accl[r] = fmaf(xv.w, w4l.w, fmaf(xv.z, w4l.z, fmaf(xv.y, w4l.y, fmaf(xv.x, w4l.x, accl[r]))));
        accr[r] = fmaf(xv.w, w4r.w, fmaf(xv.z, w4r.z, fmaf(xv.y, w4r.y, fmaf(xv.x, w4r.x, accr[r]))));
      }
    }
  }
  float bvl = bl[col0 + lane];
  float bvr = br[col0 + lane];
#pragma unroll
  for (int r = 0; r < 8; ++r) {
    int row = row0 + wid * 8 + r;
    if (row < NN) {
      Yl[(size_t)row * dout + col0 + lane] = __float2bfloat16(accl[r] + bvl);
      Yr[(size_t)row * dout + col0 + lane] = accr[r] + bvr;
    }
  }
}

// ---- fused GATv2 edge-score + softmax + aggregation ----
// wave per dst node; lane l owns channels [l*V, l*V+V); 16 lanes per head.
// Softmax with fixed shift m=0 (scores ~ +-6, e^s safe in f32; shift-invariant
// => identical math). xl gathered in bf16 (values + scores), xr/out in f32.
template <int D>
__global__ __launch_bounds__(256) void k_fused(const int* __restrict__ rowptr, const int* __restrict__ srcidx,
                                               const __hip_bfloat16* __restrict__ xl, const float* __restrict__ xr,
                                               const float* __restrict__ att, const float* __restrict__ bias,
                                               float* __restrict__ out) {
  constexpr int V = D / 64;   // 2 (layer1) or 4 (layer2)
  int lane = threadIdx.x & 63;
  int node = blockIdx.x * 4 + (threadIdx.x >> 6);
  if (node >= NN) return;
  int lo = rowptr[node], hi = rowptr[node + 1];

  float xrv[V], attv[V];
#pragma unroll
  for (int q = 0; q < V; ++q) {
    xrv[q]  = xr[(size_t)node * D + lane * V + q];
    attv[q] = att[lane * V + q];
  }

  const unsigned* xl1 = (const unsigned*)xl;   // V==2: one dword per lane
  const uint2*    xl2 = (const uint2*)xl;      // V==4: 8B per lane

  float denom = 0.f;
  float acc[V] = {};

  auto gather = [&](int j, float* xv) {
    if constexpr (V == 2) {
      unsigned u = xl1[(size_t)j * (D / 2) + lane];
      xv[0] = bflo(u); xv[1] = bfhi(u);
    } else {
      uint2 u = xl2[(size_t)j * (D / 4) + lane];
      xv[0] = bflo(u.x); xv[1] = bfhi(u.x);
      xv[2] = bflo(u.y); xv[3] = bfhi(u.y);
    }
  };
  auto score_partial = [&](const float* xv) {
    float p = 0.f;
#pragma unroll
    for (int q = 0; q < V; ++q) p += attv[q] * lrelu02(xv[q] + xrv[q]);
    return p;
  };
  auto update = [&](float sh, const float* xv) {
    float w = __expf(sh);
    denom += w;
#pragma unroll
    for (int q = 0; q < V; ++q) acc[q] += w * xv[q];
  };

  int s = lo;
  for (; s + 3 < hi; s += 4) {
    int j0 = srcidx[s], j1 = srcidx[s + 1], j2 = srcidx[s + 2], j3 = srcidx[s + 3];
    float xv0[V], xv1[V], xv2[V], xv3[V];
    gather(j0, xv0); gather(j1, xv1); gather(j2, xv2); gather(j3, xv3);
    float p0 = score_partial(xv0);
    float p1 = score_partial(xv1);
    float p2 = score_partial(xv2);
    float p3 = score_partial(xv3);
#pragma unroll
    for (int off = 1; off < 16; off <<= 1) {
      p0 += __shfl_xor(p0, off);
      p1 += __shfl_xor(p1, off);
      p2 += __shfl_xor(p2, off);
      p3 += __shfl_xor(p3, off);
    }
    update(p0, xv0); update(p1, xv1); update(p2, xv2); update(p3, xv3);
  }
  for (; s < hi; ++s) {
    int j0 = srcidx[s];
    float xv0[V];
    gather(j0, xv0);
    float p0 = score_partial(xv0);
#pragma unroll
    for (int off = 1; off < 16; off <<= 1) p0 += __shfl_xor(p0, off);
    update(p0, xv0);
  }

  float rd = 1.0f / denom;
#pragma unroll
  for (int q = 0; q < V; ++q) {
    int ch = lane * V + q;
    out[(size_t)node * D + ch] = eluf(acc[q] * rd + bias[ch]);
  }
}

__device__ __forceinline__ int lowerb(const int* __restrict__ a, int n, int v) {
  int lo = 0, hi = n;
  while (lo < hi) { int mid = (lo + hi) >> 1; if (a[mid] < v) lo = mid + 1; else hi = mid; }
  return lo;
}

__global__ __launch_bounds__(256) void k_pool(const float* __restrict__ h2, const int* __restrict__ batch,
                                              float* __restrict__ pooled) {
  int g = blockIdx.x, t = threadIdx.x;
  int lo = lowerb(batch, NN, g);
  int hi = lowerb(batch, NN, g + 1);
  float acc = 0.f;
  for (int n = lo; n < hi; ++n) acc += h2[(size_t)n * 256 + t];
  float cnt = (float)(hi - lo);
  pooled[g * 256 + t] = acc / fmaxf(cnt, 1.0f);
}

__global__ __launch_bounds__(128) void k_cls(const float* __restrict__ pooled, const float* __restrict__ Wf1,
                                             const float* __restrict__ bf1, const float* __restrict__ Wf2,
                                             const float* __restrict__ bf2, float* __restrict__ out) {
  __shared__ float p[256];
  __shared__ float z[128];
  int g = blockIdx.x, t = threadIdx.x;
  p[t] = pooled[g * 256 + t];
  p[t + 128] = pooled[g * 256 + t + 128];
  __syncthreads();
  float a = bf1[t];
  const float* wr = Wf1 + (size_t)t * 256;
  for (int k = 0; k < 256; ++k) a += p[k] * wr[k];
  z[t] = fmaxf(a, 0.f);
  __syncthreads();
  if (t < 8) {
    float o = bf2[t];
    const float* w2 = Wf2 + t * 128;
    for (int k = 0; k < 128; ++k) o += z[k] * w2[k];
    out[g * 8 + t] = o;
  }
}

extern "C" void kernel_launch(void* const* d_in, const int* in_sizes, int n_in,
                              void* d_out, int out_size, void* d_ws, size_t ws_size,
                              hipStream_t stream) {
  const float* x     = (const float*)d_in[0];
  const int*   ei    = (const int*)d_in[1];
  const int*   batch = (const int*)d_in[2];
  const float* Wl1 = (const float*)d_in[3];
  const float* bl1 = (const float*)d_in[4];
  const float* Wr1 = (const float*)d_in[5];
  const float* br1 = (const float*)d_in[6];
  const float* att1  = (const float*)d_in[7];
  const float* bias1 = (const float*)d_in[8];
  const float* Wl2 = (const float*)d_in[9];
  const float* bl2 = (const float*)d_in[10];
  const float* Wr2 = (const float*)d_in[11];
  const float* br2 = (const float*)d_in[12];
  const float* att2  = (const float*)d_in[13];
  const float* bias2 = (const float*)d_in[14];
  const float* Wf1 = (const float*)d_in[15];
  const float* bf1 = (const float*)d_in[16];
  const float* Wf2 = (const float*)d_in[17];
  const float* bf2 = (const float*)d_in[18];
  float* out = (float*)d_out;

  char* w = (char*)d_ws;
  size_t off = 0;
  auto alloc = [&](size_t bytes) -> void* {
    void* p = w + off;
    off += (bytes + 255) & ~(size_t)255;
    return p;
  };
  int* rowptr = (int*)alloc((NN + 1) * sizeof(int));
  int* deg    = (int*)alloc(NN * sizeof(int));
  int* fill   = (int*)alloc(NN * sizeof(int));
  int* srcidx = (int*)alloc((size_t)NEP * sizeof(int));
  // region A: xl1(bf16 12.8MB) + xr1(f32 25.6MB), later reused for xl2(bf16 25.6MB)
  char* regA  = (char*)alloc((size_t)NN * 128 * 2 + (size_t)NN * 128 * 4);
  __hip_bfloat16* xl1 = (__hip_bfloat16*)regA;
  float*          xr1 = (float*)(regA + (size_t)NN * 128 * 2);
  __hip_bfloat16* xl2 = (__hip_bfloat16*)regA;          // overlays xl1+xr1 (dead by then)
  float* h1     = (float*)alloc((size_t)NN * 128 * sizeof(float));
  float* xr2    = (float*)alloc((size_t)NN * 256 * sizeof(float));
  float* h2     = xr2;                                   // in-place: each node reads its xr row before writing
  float* pooled = (float*)alloc((size_t)NG * 256 * sizeof(float));
  (void)ws_size; (void)in_sizes; (void)n_in; (void)out_size;

  hipMemsetAsync(deg, 0, NN * sizeof(int), stream);
  hipMemsetAsync(fill, 0, NN * sizeof(int), stream);

  const int EB = (NEP + 255) / 256;
  k_deg<<<EB, 256, 0, stream>>>(ei, deg);
  k_scan<<<1, 1024, 0, stream>>>(deg, rowptr);
  k_scatter<<<EB, 256, 0, stream>>>(ei, rowptr, fill, srcidx);

  const int RB = (NN + 31) / 32;
  // ---- layer 1 (64 -> 4x32) ----
  dim3 g1(RB, 2);
  k_gemm2<64><<<g1, 256, 0, stream>>>(x, Wl1, bl1, Wr1, br1, xl1, xr1, 128);
  k_fused<128><<<(NN + 3) / 4, 256, 0, stream>>>(rowptr, srcidx, xl1, xr1, att1, bias1, h1);

  // ---- layer 2 (128 -> 4x64) ----
  dim3 g2(RB, 4);
  k_gemm2<128><<<g2, 256, 0, stream>>>(h1, Wl2, bl2, Wr2, br2, xl2, xr2, 256);
  k_fused<256><<<(NN + 3) / 4, 256, 0, stream>>>(rowptr, srcidx, xl2, xr2, att2, bias2, h2);

  // ---- pool + classifier ----
  k_pool<<<NG, 256, 0, stream>>>(h2, batch, pooled);
  k_cls<<<NG, 128, 0, stream>>>(pooled, Wf1, bf1, Wf2, bf2, out);
}

// Round 7
// 613.606 us; speedup vs baseline: 3.2743x; 3.2743x over previous
//
#include <hip/hip_runtime.h>
#include <hip/hip_bf16.h>
#include <math.h>

#define NN 50000
#define NE 800000
#define NEP (NE + NN)   /* edges + self loops */
#define NG 128

__device__ __forceinline__ float lrelu02(float v) {
  return fmaxf(v, 0.0f) + 0.2f * fminf(v, 0.0f);
}
__device__ __forceinline__ float eluf(float v) {
  return v > 0.0f ? v : expm1f(v);
}
__device__ __forceinline__ float bflo(unsigned u) {
  union { unsigned i; float f; } c; c.i = u << 16; return c.f;
}
__device__ __forceinline__ float bfhi(unsigned u) {
  union { unsigned i; float f; } c; c.i = u & 0xffff0000u; return c.f;
}

__global__ __launch_bounds__(256) void k_deg(const int* __restrict__ ei, int* __restrict__ deg) {
  int t = blockIdx.x * 256 + threadIdx.x;
  if (t >= NEP) return;
  int dst = (t < NE) ? ei[NE + t] : (t - NE);
  atomicAdd(&deg[dst], 1);
}

__global__ __launch_bounds__(1024) void k_scan(const int* __restrict__ deg, int* __restrict__ rowptr) {
  __shared__ int part[1024];
  int t = threadIdx.x;
  const int CH = (NN + 1023) >> 10;          // 49
  int b = t * CH;
  int e = min(b + CH, NN);
  int s = 0;
  for (int i = b; i < e; ++i) s += deg[i];
  part[t] = s;
  __syncthreads();
  for (int off = 1; off < 1024; off <<= 1) {
    int v = (t >= off) ? part[t - off] : 0;
    __syncthreads();
    part[t] += v;
    __syncthreads();
  }
  int run = (t == 0) ? 0 : part[t - 1];
  for (int i = b; i < e; ++i) { rowptr[i] = run; run += deg[i]; }
  if (t == 1023) rowptr[NN] = part[1023];
}

__global__ __launch_bounds__(256) void k_scatter(const int* __restrict__ ei, const int* __restrict__ rowptr,
                                                 int* __restrict__ fill, int* __restrict__ srcidx) {
  int t = blockIdx.x * 256 + threadIdx.x;
  if (t >= NEP) return;
  int src, dst;
  if (t < NE) { src = ei[t]; dst = ei[NE + t]; } else { src = t - NE; dst = src; }
  int pos = atomicAdd(&fill[dst], 1);
  srcidx[rowptr[dst] + pos] = src;
}

// ---- dual GEMM: Yl = X@Wl^T+bl (bf16 out), Yr = X@Wr^T+br (f32 out) ----
// Dataflow (r6 lesson: previous version was LDS-pipe-bound at ~150us):
//  - X: NO LDS. Each wave owns 8 disjoint rows, read as wave-uniform broadcast
//    global loads (L1/L2-served, VMEM pipe).
//  - W: only thing in LDS, padded [..][129] (pad proven r5/r6: conflicts->0).
//  - lane owns 2 output cols (lane, lane+64) -> 4 spread LDS reads + 128 fmaf/k4.
//  - k-loop carries explicit "#pragma unroll 1": r5/r6 proved the compiler
//    otherwise fully unrolls, hoists all loads, and spills (VGPR 256).
// Block = 4 waves x 8 rows = 32 rows x 128 cols.
template <int DIN>
__global__ __launch_bounds__(256) void k_gemm2(const float* __restrict__ X,
                                               const float* __restrict__ Wl, const float* __restrict__ bl,
                                               const float* __restrict__ Wr, const float* __restrict__ br,
                                               __hip_bfloat16* __restrict__ Yl, float* __restrict__ Yr,
                                               int dout) {
  constexpr int K4 = DIN / 4;
  constexpr int K4H = 8;               // W staged in 8-k4 chunks (33KB LDS total)
  constexpr int NST = K4 / K4H;
  __shared__ float4 wls[K4H][129];
  __shared__ float4 wrs[K4H][129];
  int t = threadIdx.x;
  int lane = t & 63;
  int wid = t >> 6;
  int row0 = blockIdx.x * 32 + wid * 8;
  int col0 = blockIdx.y * 128;

  const float4* xp[8];
#pragma unroll
  for (int r = 0; r < 8; ++r) {
    xp[r] = (const float4*)(X + (size_t)min(row0 + r, NN - 1) * DIN);
  }

  float accl0[8] = {}, accl1[8] = {};
  float accr0[8] = {}, accr1[8] = {};
  for (int st = 0; st < NST; ++st) {
    __syncthreads();   // previous stage's compute done
    for (int s = t; s < 128 * K4H; s += 256) {
      int c = s / K4H, k = s % K4H;    // 8 consecutive threads stage one W row chunk
      wls[k][c] = ((const float4*)(Wl + (size_t)(col0 + c) * DIN))[st * K4H + k];
      wrs[k][c] = ((const float4*)(Wr + (size_t)(col0 + c) * DIN))[st * K4H + k];
    }
    __syncthreads();
#pragma unroll 1
    for (int k = 0; k < K4H; ++k) {
      float4 wl0 = wls[k][lane], wl1 = wls[k][lane + 64];
      float4 wr0 = wrs[k][lane], wr1 = wrs[k][lane + 64];
      int k4 = st * K4H + k;
#pragma unroll
      for (int r = 0; r < 8; ++r) {
        float4 xv = xp[r][k4];
        accl0[r] = fmaf(xv.w, wl0.w, fmaf(xv.z, wl0.z, fmaf(xv.y, wl0.y, fmaf(xv.x, wl0.x, accl0[r]))));
        accl1[r] = fmaf(xv.w, wl1.w, fmaf(xv.z, wl1.z, fmaf(xv.y, wl1.y, fmaf(xv.x, wl1.x, accl1[r]))));
        accr0[r] = fmaf(xv.w, wr0.w, fmaf(xv.z, wr0.z, fmaf(xv.y, wr0.y, fmaf(xv.x, wr0.x, accr0[r]))));
        accr1[r] = fmaf(xv.w, wr1.w, fmaf(xv.z, wr1.z, fmaf(xv.y, wr1.y, fmaf(xv.x, wr1.x, accr1[r]))));
      }
    }
  }
  int c0 = col0 + lane, c1 = col0 + 64 + lane;
  float bvl0 = bl[c0], bvl1 = bl[c1];
  float bvr0 = br[c0], bvr1 = br[c1];
#pragma unroll
  for (int r = 0; r < 8; ++r) {
    int row = row0 + r;
    if (row < NN) {
      Yl[(size_t)row * dout + c0] = __float2bfloat16(accl0[r] + bvl0);
      Yl[(size_t)row * dout + c1] = __float2bfloat16(accl1[r] + bvl1);
      Yr[(size_t)row * dout + c0] = accr0[r] + bvr0;
      Yr[(size_t)row * dout + c1] = accr1[r] + bvr1;
    }
  }
}

// ---- fused GATv2 edge-score + softmax + aggregation ----
// wave per dst node; lane l owns channels [l*V, l*V+V); 16 lanes per head.
// Softmax with fixed shift m=0 (scores ~ +-6, e^s safe in f32; shift-invariant
// => identical math). xl gathered in bf16 (values + scores), xr/out in f32.
template <int D>
__global__ __launch_bounds__(256) void k_fused(const int* __restrict__ rowptr, const int* __restrict__ srcidx,
                                               const __hip_bfloat16* __restrict__ xl, const float* __restrict__ xr,
                                               const float* __restrict__ att, const float* __restrict__ bias,
                                               float* __restrict__ out) {
  constexpr int V = D / 64;   // 2 (layer1) or 4 (layer2)
  int lane = threadIdx.x & 63;
  int node = blockIdx.x * 4 + (threadIdx.x >> 6);
  if (node >= NN) return;
  int lo = rowptr[node], hi = rowptr[node + 1];

  float xrv[V], attv[V];
#pragma unroll
  for (int q = 0; q < V; ++q) {
    xrv[q]  = xr[(size_t)node * D + lane * V + q];
    attv[q] = att[lane * V + q];
  }

  const unsigned* xl1 = (const unsigned*)xl;   // V==2: one dword per lane
  const uint2*    xl2 = (const uint2*)xl;      // V==4: 8B per lane

  float denom = 0.f;
  float acc[V] = {};

  auto gather = [&](int j, float* xv) {
    if constexpr (V == 2) {
      unsigned u = xl1[(size_t)j * (D / 2) + lane];
      xv[0] = bflo(u); xv[1] = bfhi(u);
    } else {
      uint2 u = xl2[(size_t)j * (D / 4) + lane];
      xv[0] = bflo(u.x); xv[1] = bfhi(u.x);
      xv[2] = bflo(u.y); xv[3] = bfhi(u.y);
    }
  };
  auto score_partial = [&](const float* xv) {
    float p = 0.f;
#pragma unroll
    for (int q = 0; q < V; ++q) p += attv[q] * lrelu02(xv[q] + xrv[q]);
    return p;
  };
  auto update = [&](float sh, const float* xv) {
    float w = __expf(sh);
    denom += w;
#pragma unroll
    for (int q = 0; q < V; ++q) acc[q] += w * xv[q];
  };

  int s = lo;
  for (; s + 3 < hi; s += 4) {
    int j0 = srcidx[s], j1 = srcidx[s + 1], j2 = srcidx[s + 2], j3 = srcidx[s + 3];
    float xv0[V], xv1[V], xv2[V], xv3[V];
    gather(j0, xv0); gather(j1, xv1); gather(j2, xv2); gather(j3, xv3);
    float p0 = score_partial(xv0);
    float p1 = score_partial(xv1);
    float p2 = score_partial(xv2);
    float p3 = score_partial(xv3);
#pragma unroll
    for (int off = 1; off < 16; off <<= 1) {
      p0 += __shfl_xor(p0, off);
      p1 += __shfl_xor(p1, off);
      p2 += __shfl_xor(p2, off);
      p3 += __shfl_xor(p3, off);
    }
    update(p0, xv0); update(p1, xv1); update(p2, xv2); update(p3, xv3);
  }
  for (; s < hi; ++s) {
    int j0 = srcidx[s];
    float xv0[V];
    gather(j0, xv0);
    float p0 = score_partial(xv0);
#pragma unroll
    for (int off = 1; off < 16; off <<= 1) p0 += __shfl_xor(p0, off);
    update(p0, xv0);
  }

  float rd = 1.0f / denom;
#pragma unroll
  for (int q = 0; q < V; ++q) {
    int ch = lane * V + q;
    out[(size_t)node * D + ch] = eluf(acc[q] * rd + bias[ch]);
  }
}

__device__ __forceinline__ int lowerb(const int* __restrict__ a, int n, int v) {
  int lo = 0, hi = n;
  while (lo < hi) { int mid = (lo + hi) >> 1; if (a[mid] < v) lo = mid + 1; else hi = mid; }
  return lo;
}

__global__ __launch_bounds__(256) void k_pool(const float* __restrict__ h2, const int* __restrict__ batch,
                                              float* __restrict__ pooled) {
  int g = blockIdx.x, t = threadIdx.x;
  int lo = lowerb(batch, NN, g);
  int hi = lowerb(batch, NN, g + 1);
  float acc = 0.f;
  for (int n = lo; n < hi; ++n) acc += h2[(size_t)n * 256 + t];
  float cnt = (float)(hi - lo);
  pooled[g * 256 + t] = acc / fmaxf(cnt, 1.0f);
}

__global__ __launch_bounds__(128) void k_cls(const float* __restrict__ pooled, const float* __restrict__ Wf1,
                                             const float* __restrict__ bf1, const float* __restrict__ Wf2,
                                             const float* __restrict__ bf2, float* __restrict__ out) {
  __shared__ float p[256];
  __shared__ float z[128];
  int g = blockIdx.x, t = threadIdx.x;
  p[t] = pooled[g * 256 + t];
  p[t + 128] = pooled[g * 256 + t + 128];
  __syncthreads();
  float a = bf1[t];
  const float* wr = Wf1 + (size_t)t * 256;
  for (int k = 0; k < 256; ++k) a += p[k] * wr[k];
  z[t] = fmaxf(a, 0.f);
  __syncthreads();
  if (t < 8) {
    float o = bf2[t];
    const float* w2 = Wf2 + t * 128;
    for (int k = 0; k < 128; ++k) o += z[k] * w2[k];
    out[g * 8 + t] = o;
  }
}

extern "C" void kernel_launch(void* const* d_in, const int* in_sizes, int n_in,
                              void* d_out, int out_size, void* d_ws, size_t ws_size,
                              hipStream_t stream) {
  const float* x     = (const float*)d_in[0];
  const int*   ei    = (const int*)d_in[1];
  const int*   batch = (const int*)d_in[2];
  const float* Wl1 = (const float*)d_in[3];
  const float* bl1 = (const float*)d_in[4];
  const float* Wr1 = (const float*)d_in[5];
  const float* br1 = (const float*)d_in[6];
  const float* att1  = (const float*)d_in[7];
  const float* bias1 = (const float*)d_in[8];
  const float* Wl2 = (const float*)d_in[9];
  const float* bl2 = (const float*)d_in[10];
  const float* Wr2 = (const float*)d_in[11];
  const float* br2 = (const float*)d_in[12];
  const float* att2  = (const float*)d_in[13];
  const float* bias2 = (const float*)d_in[14];
  const float* Wf1 = (const float*)d_in[15];
  const float* bf1 = (const float*)d_in[16];
  const float* Wf2 = (const float*)d_in[17];
  const float* bf2 = (const float*)d_in[18];
  float* out = (float*)d_out;

  char* w = (char*)d_ws;
  size_t off = 0;
  auto alloc = [&](size_t bytes) -> void* {
    void* p = w + off;
    off += (bytes + 255) & ~(size_t)255;
    return p;
  };
  int* rowptr = (int*)alloc((NN + 1) * sizeof(int));
  int* deg    = (int*)alloc(NN * sizeof(int));
  int* fill   = (int*)alloc(NN * sizeof(int));
  int* srcidx = (int*)alloc((size_t)NEP * sizeof(int));
  // region A: xl1(bf16 12.8MB) + xr1(f32 25.6MB), later reused for xl2(bf16 25.6MB)
  char* regA  = (char*)alloc((size_t)NN * 128 * 2 + (size_t)NN * 128 * 4);
  __hip_bfloat16* xl1 = (__hip_bfloat16*)regA;
  float*          xr1 = (float*)(regA + (size_t)NN * 128 * 2);
  __hip_bfloat16* xl2 = (__hip_bfloat16*)regA;          // overlays xl1+xr1 (dead by then)
  float* h1     = (float*)alloc((size_t)NN * 128 * sizeof(float));
  float* xr2    = (float*)alloc((size_t)NN * 256 * sizeof(float));
  float* h2     = xr2;                                   // in-place: each node reads its xr row before writing
  float* pooled = (float*)alloc((size_t)NG * 256 * sizeof(float));
  (void)ws_size; (void)in_sizes; (void)n_in; (void)out_size;

  hipMemsetAsync(deg, 0, NN * sizeof(int), stream);
  hipMemsetAsync(fill, 0, NN * sizeof(int), stream);

  const int EB = (NEP + 255) / 256;
  k_deg<<<EB, 256, 0, stream>>>(ei, deg);
  k_scan<<<1, 1024, 0, stream>>>(deg, rowptr);
  k_scatter<<<EB, 256, 0, stream>>>(ei, rowptr, fill, srcidx);

  const int RB = (NN + 31) / 32;
  // ---- layer 1 (64 -> 4x32) ----
  dim3 g1(RB, 1);
  k_gemm2<64><<<g1, 256, 0, stream>>>(x, Wl1, bl1, Wr1, br1, xl1, xr1, 128);
  k_fused<128><<<(NN + 3) / 4, 256, 0, stream>>>(rowptr, srcidx, xl1, xr1, att1, bias1, h1);

  // ---- layer 2 (128 -> 4x64) ----
  dim3 g2(RB, 2);
  k_gemm2<128><<<g2, 256, 0, stream>>>(h1, Wl2, bl2, Wr2, br2, xl2, xr2, 256);
  k_fused<256><<<(NN + 3) / 4, 256, 0, stream>>>(rowptr, srcidx, xl2, xr2, att2, bias2, h2);

  // ---- pool + classifier ----
  k_pool<<<NG, 256, 0, stream>>>(h2, batch, pooled);
  k_cls<<<NG, 128, 0, stream>>>(pooled, Wf1, bf1, Wf2, bf2, out);
}

// Round 8
// 601.808 us; speedup vs baseline: 3.3385x; 1.0196x over previous
//
#include <hip/hip_runtime.h>
#include <hip/hip_bf16.h>
#include <math.h>

#define NN 50000
#define NE 800000
#define NEP (NE + NN)   /* edges + self loops */
#define NG 128

__device__ __forceinline__ float lrelu02(float v) {
  return fmaxf(v, 0.0f) + 0.2f * fminf(v, 0.0f);
}
__device__ __forceinline__ float eluf(float v) {
  return v > 0.0f ? v : expm1f(v);
}
__device__ __forceinline__ float bflo(unsigned u) {
  union { unsigned i; float f; } c; c.i = u << 16; return c.f;
}
__device__ __forceinline__ float bfhi(unsigned u) {
  union { unsigned i; float f; } c; c.i = u & 0xffff0000u; return c.f;
}

__global__ __launch_bounds__(256) void k_deg(const int* __restrict__ ei, int* __restrict__ deg) {
  int t = blockIdx.x * 256 + threadIdx.x;
  if (t >= NEP) return;
  int dst = (t < NE) ? ei[NE + t] : (t - NE);
  atomicAdd(&deg[dst], 1);
}

__global__ __launch_bounds__(1024) void k_scan(const int* __restrict__ deg, int* __restrict__ rowptr) {
  __shared__ int part[1024];
  int t = threadIdx.x;
  const int CH = (NN + 1023) >> 10;          // 49
  int b = t * CH;
  int e = min(b + CH, NN);
  int s = 0;
  for (int i = b; i < e; ++i) s += deg[i];
  part[t] = s;
  __syncthreads();
  for (int off = 1; off < 1024; off <<= 1) {
    int v = (t >= off) ? part[t - off] : 0;
    __syncthreads();
    part[t] += v;
    __syncthreads();
  }
  int run = (t == 0) ? 0 : part[t - 1];
  for (int i = b; i < e; ++i) { rowptr[i] = run; run += deg[i]; }
  if (t == 1023) rowptr[NN] = part[1023];
}

__global__ __launch_bounds__(256) void k_scatter(const int* __restrict__ ei, const int* __restrict__ rowptr,
                                                 int* __restrict__ fill, int* __restrict__ srcidx) {
  int t = blockIdx.x * 256 + threadIdx.x;
  if (t >= NEP) return;
  int src, dst;
  if (t < NE) { src = ei[t]; dst = ei[NE + t]; } else { src = t - NE; dst = src; }
  int pos = atomicAdd(&fill[dst], 1);
  srcidx[rowptr[dst] + pos] = src;
}

// ---- dual GEMM: Yl = X@Wl^T+bl (bf16 out), Yr = X@Wr^T+br (f32 out) ----
//  - X: no LDS; wave-uniform broadcast global loads from ONE base pointer with
//    immediate offsets (row0 clamped to NN-8: boundary blocks recompute the same
//    rows and write identical values - benign).
//  - 1-deep software prefetch, k advanced in pairs (ping-pong xA/xB, no copies):
//    X latency for k+1 hides under the 256-cyc fmaf block of k. (r7: VALUBusy
//    45%, 55% latency stall without this.)
//  - W: LDS, padded [..][129] (r5-r7: staging conflicts 0).
//  - k-loop keeps explicit "#pragma unroll 1" (r5/r6: default codegen fully
//    unrolls, hoists, and spills at VGPR 256).
// Block = 4 waves x 8 rows = 32 rows x 128 cols.
template <int DIN>
__global__ __launch_bounds__(256) void k_gemm2(const float* __restrict__ X,
                                               const float* __restrict__ Wl, const float* __restrict__ bl,
                                               const float* __restrict__ Wr, const float* __restrict__ br,
                                               __hip_bfloat16* __restrict__ Yl, float* __restrict__ Yr,
                                               int dout) {
  constexpr int K4 = DIN / 4;
  constexpr int K4H = 8;               // W staged in 8-k4 chunks (33KB LDS total)
  constexpr int NST = K4 / K4H;
  __shared__ float4 wls[K4H][129];
  __shared__ float4 wrs[K4H][129];
  int t = threadIdx.x;
  int lane = t & 63;
  int wid = t >> 6;
  int row0 = blockIdx.x * 32 + wid * 8;
  row0 = min(row0, NN - 8);
  int col0 = blockIdx.y * 128;

  const float4* xb = (const float4*)(X + (size_t)row0 * DIN);   // xb[r*K4 + k4], imm offsets

  float accl0[8] = {}, accl1[8] = {};
  float accr0[8] = {}, accr1[8] = {};
  float4 xA[8], xB[8];
#pragma unroll
  for (int r = 0; r < 8; ++r) xA[r] = xb[r * K4];    // prologue: k4 = 0

  for (int st = 0; st < NST; ++st) {
    __syncthreads();   // previous stage's compute done
    for (int s = t; s < 128 * K4H; s += 256) {
      int c = s / K4H, k = s % K4H;    // 8 consecutive threads stage one W row chunk
      wls[k][c] = ((const float4*)(Wl + (size_t)(col0 + c) * DIN))[st * K4H + k];
      wrs[k][c] = ((const float4*)(Wr + (size_t)(col0 + c) * DIN))[st * K4H + k];
    }
    __syncthreads();
#pragma unroll 1
    for (int k = 0; k < K4H; k += 2) {
      int k4 = st * K4H + k;
      int kp1 = min(k4 + 1, K4 - 1);
      int kp2 = min(k4 + 2, K4 - 1);
      // ---- sub-iter A: prefetch k4+1 into xB, compute k4 from xA ----
      {
        float4 wl0 = wls[k][lane], wl1 = wls[k][lane + 64];
        float4 wr0 = wrs[k][lane], wr1 = wrs[k][lane + 64];
#pragma unroll
        for (int r = 0; r < 8; ++r) xB[r] = xb[r * K4 + kp1];
#pragma unroll
        for (int r = 0; r < 8; ++r) {
          float4 xv = xA[r];
          accl0[r] = fmaf(xv.w, wl0.w, fmaf(xv.z, wl0.z, fmaf(xv.y, wl0.y, fmaf(xv.x, wl0.x, accl0[r]))));
          accl1[r] = fmaf(xv.w, wl1.w, fmaf(xv.z, wl1.z, fmaf(xv.y, wl1.y, fmaf(xv.x, wl1.x, accl1[r]))));
          accr0[r] = fmaf(xv.w, wr0.w, fmaf(xv.z, wr0.z, fmaf(xv.y, wr0.y, fmaf(xv.x, wr0.x, accr0[r]))));
          accr1[r] = fmaf(xv.w, wr1.w, fmaf(xv.z, wr1.z, fmaf(xv.y, wr1.y, fmaf(xv.x, wr1.x, accr1[r]))));
        }
      }
      // ---- sub-iter B: prefetch k4+2 into xA, compute k4+1 from xB ----
      {
        float4 wl0 = wls[k + 1][lane], wl1 = wls[k + 1][lane + 64];
        float4 wr0 = wrs[k + 1][lane], wr1 = wrs[k + 1][lane + 64];
#pragma unroll
        for (int r = 0; r < 8; ++r) xA[r] = xb[r * K4 + kp2];
#pragma unroll
        for (int r = 0; r < 8; ++r) {
          float4 xv = xB[r];
          accl0[r] = fmaf(xv.w, wl0.w, fmaf(xv.z, wl0.z, fmaf(xv.y, wl0.y, fmaf(xv.x, wl0.x, accl0[r]))));
          accl1[r] = fmaf(xv.w, wl1.w, fmaf(xv.z, wl1.z, fmaf(xv.y, wl1.y, fmaf(xv.x, wl1.x, accl1[r]))));
          accr0[r] = fmaf(xv.w, wr0.w, fmaf(xv.z, wr0.z, fmaf(xv.y, wr0.y, fmaf(xv.x, wr0.x, accr0[r]))));
          accr1[r] = fmaf(xv.w, wr1.w, fmaf(xv.z, wr1.z, fmaf(xv.y, wr1.y, fmaf(xv.x, wr1.x, accr1[r]))));
        }
      }
    }
  }
  int c0 = col0 + lane, c1 = col0 + 64 + lane;
  float bvl0 = bl[c0], bvl1 = bl[c1];
  float bvr0 = br[c0], bvr1 = br[c1];
#pragma unroll
  for (int r = 0; r < 8; ++r) {
    int row = row0 + r;
    Yl[(size_t)row * dout + c0] = __float2bfloat16(accl0[r] + bvl0);
    Yl[(size_t)row * dout + c1] = __float2bfloat16(accl1[r] + bvl1);
    Yr[(size_t)row * dout + c0] = accr0[r] + bvr0;
    Yr[(size_t)row * dout + c1] = accr1[r] + bvr1;
  }
}

// ---- fused GATv2 edge-score + softmax + aggregation ----
// wave per dst node; lane l owns channels [l*V, l*V+V); 16 lanes per head.
// Softmax with fixed shift m=0 (scores ~ +-6, e^s safe in f32; shift-invariant
// => identical math). xl gathered in bf16 (values + scores), xr/out in f32.
template <int D>
__global__ __launch_bounds__(256) void k_fused(const int* __restrict__ rowptr, const int* __restrict__ srcidx,
                                               const __hip_bfloat16* __restrict__ xl, const float* __restrict__ xr,
                                               const float* __restrict__ att, const float* __restrict__ bias,
                                               float* __restrict__ out) {
  constexpr int V = D / 64;   // 2 (layer1) or 4 (layer2)
  int lane = threadIdx.x & 63;
  int node = blockIdx.x * 4 + (threadIdx.x >> 6);
  if (node >= NN) return;
  int lo = rowptr[node], hi = rowptr[node + 1];

  float xrv[V], attv[V];
#pragma unroll
  for (int q = 0; q < V; ++q) {
    xrv[q]  = xr[(size_t)node * D + lane * V + q];
    attv[q] = att[lane * V + q];
  }

  const unsigned* xl1 = (const unsigned*)xl;   // V==2: one dword per lane
  const uint2*    xl2 = (const uint2*)xl;      // V==4: 8B per lane

  float denom = 0.f;
  float acc[V] = {};

  auto gather = [&](int j, float* xv) {
    if constexpr (V == 2) {
      unsigned u = xl1[(size_t)j * (D / 2) + lane];
      xv[0] = bflo(u); xv[1] = bfhi(u);
    } else {
      uint2 u = xl2[(size_t)j * (D / 4) + lane];
      xv[0] = bflo(u.x); xv[1] = bfhi(u.x);
      xv[2] = bflo(u.y); xv[3] = bfhi(u.y);
    }
  };
  auto score_partial = [&](const float* xv) {
    float p = 0.f;
#pragma unroll
    for (int q = 0; q < V; ++q) p += attv[q] * lrelu02(xv[q] + xrv[q]);
    return p;
  };
  auto update = [&](float sh, const float* xv) {
    float w = __expf(sh);
    denom += w;
#pragma unroll
    for (int q = 0; q < V; ++q) acc[q] += w * xv[q];
  };

  int s = lo;
  for (; s + 3 < hi; s += 4) {
    int j0 = srcidx[s], j1 = srcidx[s + 1], j2 = srcidx[s + 2], j3 = srcidx[s + 3];
    float xv0[V], xv1[V], xv2[V], xv3[V];
    gather(j0, xv0); gather(j1, xv1); gather(j2, xv2); gather(j3, xv3);
    float p0 = score_partial(xv0);
    float p1 = score_partial(xv1);
    float p2 = score_partial(xv2);
    float p3 = score_partial(xv3);
#pragma unroll
    for (int off = 1; off < 16; off <<= 1) {
      p0 += __shfl_xor(p0, off);
      p1 += __shfl_xor(p1, off);
      p2 += __shfl_xor(p2, off);
      p3 += __shfl_xor(p3, off);
    }
    update(p0, xv0); update(p1, xv1); update(p2, xv2); update(p3, xv3);
  }
  for (; s < hi; ++s) {
    int j0 = srcidx[s];
    float xv0[V];
    gather(j0, xv0);
    float p0 = score_partial(xv0);
#pragma unroll
    for (int off = 1; off < 16; off <<= 1) p0 += __shfl_xor(p0, off);
    update(p0, xv0);
  }

  float rd = 1.0f / denom;
#pragma unroll
  for (int q = 0; q < V; ++q) {
    int ch = lane * V + q;
    out[(size_t)node * D + ch] = eluf(acc[q] * rd + bias[ch]);
  }
}

__device__ __forceinline__ int lowerb(const int* __restrict__ a, int n, int v) {
  int lo = 0, hi = n;
  while (lo < hi) { int mid = (lo + hi) >> 1; if (a[mid] < v) lo = mid + 1; else hi = mid; }
  return lo;
}

__global__ __launch_bounds__(256) void k_pool(const float* __restrict__ h2, const int* __restrict__ batch,
                                              float* __restrict__ pooled) {
  int g = blockIdx.x, t = threadIdx.x;
  int lo = lowerb(batch, NN, g);
  int hi = lowerb(batch, NN, g + 1);
  float acc = 0.f;
  for (int n = lo; n < hi; ++n) acc += h2[(size_t)n * 256 + t];
  float cnt = (float)(hi - lo);
  pooled[g * 256 + t] = acc / fmaxf(cnt, 1.0f);
}

__global__ __launch_bounds__(128) void k_cls(const float* __restrict__ pooled, const float* __restrict__ Wf1,
                                             const float* __restrict__ bf1, const float* __restrict__ Wf2,
                                             const float* __restrict__ bf2, float* __restrict__ out) {
  __shared__ float p[256];
  __shared__ float z[128];
  int g = blockIdx.x, t = threadIdx.x;
  p[t] = pooled[g * 256 + t];
  p[t + 128] = pooled[g * 256 + t + 128];
  __syncthreads();
  float a = bf1[t];
  const float* wr = Wf1 + (size_t)t * 256;
  for (int k = 0; k < 256; ++k) a += p[k] * wr[k];
  z[t] = fmaxf(a, 0.f);
  __syncthreads();
  if (t < 8) {
    float o = bf2[t];
    const float* w2 = Wf2 + t * 128;
    for (int k = 0; k < 128; ++k) o += z[k] * w2[k];
    out[g * 8 + t] = o;
  }
}

extern "C" void kernel_launch(void* const* d_in, const int* in_sizes, int n_in,
                              void* d_out, int out_size, void* d_ws, size_t ws_size,
                              hipStream_t stream) {
  const float* x     = (const float*)d_in[0];
  const int*   ei    = (const int*)d_in[1];
  const int*   batch = (const int*)d_in[2];
  const float* Wl1 = (const float*)d_in[3];
  const float* bl1 = (const float*)d_in[4];
  const float* Wr1 = (const float*)d_in[5];
  const float* br1 = (const float*)d_in[6];
  const float* att1  = (const float*)d_in[7];
  const float* bias1 = (const float*)d_in[8];
  const float* Wl2 = (const float*)d_in[9];
  const float* bl2 = (const float*)d_in[10];
  const float* Wr2 = (const float*)d_in[11];
  const float* br2 = (const float*)d_in[12];
  const float* att2  = (const float*)d_in[13];
  const float* bias2 = (const float*)d_in[14];
  const float* Wf1 = (const float*)d_in[15];
  const float* bf1 = (const float*)d_in[16];
  const float* Wf2 = (const float*)d_in[17];
  const float* bf2 = (const float*)d_in[18];
  float* out = (float*)d_out;

  char* w = (char*)d_ws;
  size_t off = 0;
  auto alloc = [&](size_t bytes) -> void* {
    void* p = w + off;
    off += (bytes + 255) & ~(size_t)255;
    return p;
  };
  int* rowptr = (int*)alloc((NN + 1) * sizeof(int));
  int* deg    = (int*)alloc(NN * sizeof(int));
  int* fill   = (int*)alloc(NN * sizeof(int));
  int* srcidx = (int*)alloc((size_t)NEP * sizeof(int));
  // region A: xl1(bf16 12.8MB) + xr1(f32 25.6MB), later reused for xl2(bf16 25.6MB)
  char* regA  = (char*)alloc((size_t)NN * 128 * 2 + (size_t)NN * 128 * 4);
  __hip_bfloat16* xl1 = (__hip_bfloat16*)regA;
  float*          xr1 = (float*)(regA + (size_t)NN * 128 * 2);
  __hip_bfloat16* xl2 = (__hip_bfloat16*)regA;          // overlays xl1+xr1 (dead by then)
  float* h1     = (float*)alloc((size_t)NN * 128 * sizeof(float));
  float* xr2    = (float*)alloc((size_t)NN * 256 * sizeof(float));
  float* h2     = xr2;                                   // in-place: each node reads its xr row before writing
  float* pooled = (float*)alloc((size_t)NG * 256 * sizeof(float));
  (void)ws_size; (void)in_sizes; (void)n_in; (void)out_size;

  hipMemsetAsync(deg, 0, NN * sizeof(int), stream);
  hipMemsetAsync(fill, 0, NN * sizeof(int), stream);

  const int EB = (NEP + 255) / 256;
  k_deg<<<EB, 256, 0, stream>>>(ei, deg);
  k_scan<<<1, 1024, 0, stream>>>(deg, rowptr);
  k_scatter<<<EB, 256, 0, stream>>>(ei, rowptr, fill, srcidx);

  const int RB = (NN + 31) / 32;
  // ---- layer 1 (64 -> 4x32) ----
  dim3 g1(RB, 1);
  k_gemm2<64><<<g1, 256, 0, stream>>>(x, Wl1, bl1, Wr1, br1, xl1, xr1, 128);
  k_fused<128><<<(NN + 3) / 4, 256, 0, stream>>>(rowptr, srcidx, xl1, xr1, att1, bias1, h1);

  // ---- layer 2 (128 -> 4x64) ----
  dim3 g2(RB, 2);
  k_gemm2<128><<<g2, 256, 0, stream>>>(h1, Wl2, bl2, Wr2, br2, xl2, xr2, 256);
  k_fused<256><<<(NN + 3) / 4, 256, 0, stream>>>(rowptr, srcidx, xl2, xr2, att2, bias2, h2);

  // ---- pool + classifier ----
  k_pool<<<NG, 256, 0, stream>>>(h2, batch, pooled);
  k_cls<<<NG, 128, 0, stream>>>(pooled, Wf1, bf1, Wf2, bf2, out);
}

// Round 9
// 564.560 us; speedup vs baseline: 3.5587x; 1.0660x over previous
//
#include <hip/hip_runtime.h>
#include <hip/hip_bf16.h>
#include <math.h>

#define NN 50000
#define NE 800000
#define NEP (NE + NN)   /* edges + self loops */
#define NG 128

__device__ __forceinline__ float lrelu02(float v) {
  return fmaxf(v, 0.0f) + 0.2f * fminf(v, 0.0f);
}
__device__ __forceinline__ float eluf(float v) {
  return v > 0.0f ? v : expm1f(v);
}
__device__ __forceinline__ float bflo(unsigned u) {
  union { unsigned i; float f; } c; c.i = u << 16; return c.f;
}
__device__ __forceinline__ float bfhi(unsigned u) {
  union { unsigned i; float f; } c; c.i = u & 0xffff0000u; return c.f;
}

__global__ __launch_bounds__(256) void k_deg(const int* __restrict__ ei, int* __restrict__ deg) {
  int t = blockIdx.x * 256 + threadIdx.x;
  if (t >= NEP) return;
  int dst = (t < NE) ? ei[NE + t] : (t - NE);
  atomicAdd(&deg[dst], 1);
}

__global__ __launch_bounds__(1024) void k_scan(const int* __restrict__ deg, int* __restrict__ rowptr) {
  __shared__ int part[1024];
  int t = threadIdx.x;
  const int CH = (NN + 1023) >> 10;          // 49
  int b = t * CH;
  int e = min(b + CH, NN);
  int s = 0;
  for (int i = b; i < e; ++i) s += deg[i];
  part[t] = s;
  __syncthreads();
  for (int off = 1; off < 1024; off <<= 1) {
    int v = (t >= off) ? part[t - off] : 0;
    __syncthreads();
    part[t] += v;
    __syncthreads();
  }
  int run = (t == 0) ? 0 : part[t - 1];
  for (int i = b; i < e; ++i) { rowptr[i] = run; run += deg[i]; }
  if (t == 1023) rowptr[NN] = part[1023];
}

__global__ __launch_bounds__(256) void k_scatter(const int* __restrict__ ei, const int* __restrict__ rowptr,
                                                 int* __restrict__ fill, int* __restrict__ srcidx) {
  int t = blockIdx.x * 256 + threadIdx.x;
  if (t >= NEP) return;
  int src, dst;
  if (t < NE) { src = ei[t]; dst = ei[NE + t]; } else { src = t - NE; dst = src; }
  int pos = atomicAdd(&fill[dst], 1);
  srcidx[rowptr[dst] + pos] = src;
}

// ---- dual GEMM: Yl = X@Wl^T+bl (bf16 out), Yr = X@Wr^T+br (f32 out) ----
// r8 pipe arithmetic: W spread-reads from LDS are the bottleneck; LDS BROADCAST
// reads (uniform addr) cost only 16B of bank traffic. So:
//  - X tile [64][K4] in LDS, read via broadcast (cheap);
//  - each wave owns 16 rows -> one spread W-read pair feeds 128 fma;
//  - W chunks [8][65] padded (r5-r8: staging conflicts == 0);
//  - k-loop keeps "#pragma unroll 1" (r5/r6: default codegen unrolls & spills).
// Per CU: ~104 cyc LDS per ~290 cyc VALU -> VALU-bound with 2.8x headroom.
// Block = 4 waves x 16 rows = 64 rows x 64 cols.
template <int DIN>
__global__ __launch_bounds__(256) void k_gemm2(const float* __restrict__ X,
                                               const float* __restrict__ Wl, const float* __restrict__ bl,
                                               const float* __restrict__ Wr, const float* __restrict__ br,
                                               __hip_bfloat16* __restrict__ Yl, float* __restrict__ Yr,
                                               int dout) {
  constexpr int K4 = DIN / 4;          // 16 (L1) or 32 (L2)
  constexpr int K4H = 8;               // W staged in 8-k4 chunks
  constexpr int NST = K4 / K4H;
  __shared__ float4 xs[64][K4];        // 16KB / 32KB
  __shared__ float4 wls[K4H][65];      // 8.3KB each, padded: conflict-free staging
  __shared__ float4 wrs[K4H][65];
  int t = threadIdx.x;
  int lane = t & 63;
  int wid = t >> 6;
  int row0 = blockIdx.x * 64;
  int col0 = blockIdx.y * 64;

  // stage X tile (coalesced float4 reads; consecutive threads -> consecutive LDS)
  for (int s = t; s < 64 * K4; s += 256) {
    int r = s / K4, k4 = s % K4;
    int row = min(row0 + r, NN - 1);
    xs[r][k4] = ((const float4*)(X + (size_t)row * DIN))[k4];
  }

  float accl[16] = {};
  float accr[16] = {};
  for (int st = 0; st < NST; ++st) {
    __syncthreads();   // X ready (st=0) / previous chunk's compute done (st>0)
    for (int s = t; s < 64 * K4H; s += 256) {
      int c = s / K4H, k = s % K4H;    // 8 consecutive threads stage one W row chunk
      wls[k][c] = ((const float4*)(Wl + (size_t)(col0 + c) * DIN))[st * K4H + k];
      wrs[k][c] = ((const float4*)(Wr + (size_t)(col0 + c) * DIN))[st * K4H + k];
    }
    __syncthreads();
#pragma unroll 1
    for (int k = 0; k < K4H; ++k) {
      float4 wl = wls[k][lane];        // spread read, conflict-free (contiguous 16B/lane)
      float4 wr = wrs[k][lane];
      int k4 = st * K4H + k;
#pragma unroll
      for (int r = 0; r < 16; ++r) {
        float4 xv = xs[wid * 16 + r][k4];   // broadcast read (uniform addr): cheap
        accl[r] = fmaf(xv.w, wl.w, fmaf(xv.z, wl.z, fmaf(xv.y, wl.y, fmaf(xv.x, wl.x, accl[r]))));
        accr[r] = fmaf(xv.w, wr.w, fmaf(xv.z, wr.z, fmaf(xv.y, wr.y, fmaf(xv.x, wr.x, accr[r]))));
      }
    }
  }
  float bvl = bl[col0 + lane];
  float bvr = br[col0 + lane];
#pragma unroll
  for (int r = 0; r < 16; ++r) {
    int row = row0 + wid * 16 + r;
    if (row < NN) {
      Yl[(size_t)row * dout + col0 + lane] = __float2bfloat16(accl[r] + bvl);
      Yr[(size_t)row * dout + col0 + lane] = accr[r] + bvr;
    }
  }
}

// ---- fused GATv2 edge-score + softmax + aggregation ----
// wave per dst node; lane l owns channels [l*V, l*V+V); 16 lanes per head.
// Softmax with fixed shift m=0 (scores ~ +-6, e^s safe in f32; shift-invariant
// => identical math). xl gathered in bf16 (values + scores), xr/out in f32.
template <int D>
__global__ __launch_bounds__(256) void k_fused(const int* __restrict__ rowptr, const int* __restrict__ srcidx,
                                               const __hip_bfloat16* __restrict__ xl, const float* __restrict__ xr,
                                               const float* __restrict__ att, const float* __restrict__ bias,
                                               float* __restrict__ out) {
  constexpr int V = D / 64;   // 2 (layer1) or 4 (layer2)
  int lane = threadIdx.x & 63;
  int node = blockIdx.x * 4 + (threadIdx.x >> 6);
  if (node >= NN) return;
  int lo = rowptr[node], hi = rowptr[node + 1];

  float xrv[V], attv[V];
#pragma unroll
  for (int q = 0; q < V; ++q) {
    xrv[q]  = xr[(size_t)node * D + lane * V + q];
    attv[q] = att[lane * V + q];
  }

  const unsigned* xl1 = (const unsigned*)xl;   // V==2: one dword per lane
  const uint2*    xl2 = (const uint2*)xl;      // V==4: 8B per lane

  float denom = 0.f;
  float acc[V] = {};

  auto gather = [&](int j, float* xv) {
    if constexpr (V == 2) {
      unsigned u = xl1[(size_t)j * (D / 2) + lane];
      xv[0] = bflo(u); xv[1] = bfhi(u);
    } else {
      uint2 u = xl2[(size_t)j * (D / 4) + lane];
      xv[0] = bflo(u.x); xv[1] = bfhi(u.x);
      xv[2] = bflo(u.y); xv[3] = bfhi(u.y);
    }
  };
  auto score_partial = [&](const float* xv) {
    float p = 0.f;
#pragma unroll
    for (int q = 0; q < V; ++q) p += attv[q] * lrelu02(xv[q] + xrv[q]);
    return p;
  };
  auto update = [&](float sh, const float* xv) {
    float w = __expf(sh);
    denom += w;
#pragma unroll
    for (int q = 0; q < V; ++q) acc[q] += w * xv[q];
  };

  int s = lo;
  for (; s + 3 < hi; s += 4) {
    int j0 = srcidx[s], j1 = srcidx[s + 1], j2 = srcidx[s + 2], j3 = srcidx[s + 3];
    float xv0[V], xv1[V], xv2[V], xv3[V];
    gather(j0, xv0); gather(j1, xv1); gather(j2, xv2); gather(j3, xv3);
    float p0 = score_partial(xv0);
    float p1 = score_partial(xv1);
    float p2 = score_partial(xv2);
    float p3 = score_partial(xv3);
#pragma unroll
    for (int off = 1; off < 16; off <<= 1) {
      p0 += __shfl_xor(p0, off);
      p1 += __shfl_xor(p1, off);
      p2 += __shfl_xor(p2, off);
      p3 += __shfl_xor(p3, off);
    }
    update(p0, xv0); update(p1, xv1); update(p2, xv2); update(p3, xv3);
  }
  for (; s < hi; ++s) {
    int j0 = srcidx[s];
    float xv0[V];
    gather(j0, xv0);
    float p0 = score_partial(xv0);
#pragma unroll
    for (int off = 1; off < 16; off <<= 1) p0 += __shfl_xor(p0, off);
    update(p0, xv0);
  }

  float rd = 1.0f / denom;
#pragma unroll
  for (int q = 0; q < V; ++q) {
    int ch = lane * V + q;
    out[(size_t)node * D + ch] = eluf(acc[q] * rd + bias[ch]);
  }
}

__device__ __forceinline__ int lowerb(const int* __restrict__ a, int n, int v) {
  int lo = 0, hi = n;
  while (lo < hi) { int mid = (lo + hi) >> 1; if (a[mid] < v) lo = mid + 1; else hi = mid; }
  return lo;
}

__global__ __launch_bounds__(256) void k_pool(const float* __restrict__ h2, const int* __restrict__ batch,
                                              float* __restrict__ pooled) {
  int g = blockIdx.x, t = threadIdx.x;
  int lo = lowerb(batch, NN, g);
  int hi = lowerb(batch, NN, g + 1);
  float acc = 0.f;
  for (int n = lo; n < hi; ++n) acc += h2[(size_t)n * 256 + t];
  float cnt = (float)(hi - lo);
  pooled[g * 256 + t] = acc / fmaxf(cnt, 1.0f);
}

__global__ __launch_bounds__(128) void k_cls(const float* __restrict__ pooled, const float* __restrict__ Wf1,
                                             const float* __restrict__ bf1, const float* __restrict__ Wf2,
                                             const float* __restrict__ bf2, float* __restrict__ out) {
  __shared__ float p[256];
  __shared__ float z[128];
  int g = blockIdx.x, t = threadIdx.x;
  p[t] = pooled[g * 256 + t];
  p[t + 128] = pooled[g * 256 + t + 128];
  __syncthreads();
  float a = bf1[t];
  const float* wr = Wf1 + (size_t)t * 256;
  for (int k = 0; k < 256; ++k) a += p[k] * wr[k];
  z[t] = fmaxf(a, 0.f);
  __syncthreads();
  if (t < 8) {
    float o = bf2[t];
    const float* w2 = Wf2 + t * 128;
    for (int k = 0; k < 128; ++k) o += z[k] * w2[k];
    out[g * 8 + t] = o;
  }
}

extern "C" void kernel_launch(void* const* d_in, const int* in_sizes, int n_in,
                              void* d_out, int out_size, void* d_ws, size_t ws_size,
                              hipStream_t stream) {
  const float* x     = (const float*)d_in[0];
  const int*   ei    = (const int*)d_in[1];
  const int*   batch = (const int*)d_in[2];
  const float* Wl1 = (const float*)d_in[3];
  const float* bl1 = (const float*)d_in[4];
  const float* Wr1 = (const float*)d_in[5];
  const float* br1 = (const float*)d_in[6];
  const float* att1  = (const float*)d_in[7];
  const float* bias1 = (const float*)d_in[8];
  const float* Wl2 = (const float*)d_in[9];
  const float* bl2 = (const float*)d_in[10];
  const float* Wr2 = (const float*)d_in[11];
  const float* br2 = (const float*)d_in[12];
  const float* att2  = (const float*)d_in[13];
  const float* bias2 = (const float*)d_in[14];
  const float* Wf1 = (const float*)d_in[15];
  const float* bf1 = (const float*)d_in[16];
  const float* Wf2 = (const float*)d_in[17];
  const float* bf2 = (const float*)d_in[18];
  float* out = (float*)d_out;

  char* w = (char*)d_ws;
  size_t off = 0;
  auto alloc = [&](size_t bytes) -> void* {
    void* p = w + off;
    off += (bytes + 255) & ~(size_t)255;
    return p;
  };
  int* rowptr = (int*)alloc((NN + 1) * sizeof(int));
  int* deg    = (int*)alloc(NN * sizeof(int));
  int* fill   = (int*)alloc(NN * sizeof(int));
  int* srcidx = (int*)alloc((size_t)NEP * sizeof(int));
  // region A: xl1(bf16 12.8MB) + xr1(f32 25.6MB), later reused for xl2(bf16 25.6MB)
  char* regA  = (char*)alloc((size_t)NN * 128 * 2 + (size_t)NN * 128 * 4);
  __hip_bfloat16* xl1 = (__hip_bfloat16*)regA;
  float*          xr1 = (float*)(regA + (size_t)NN * 128 * 2);
  __hip_bfloat16* xl2 = (__hip_bfloat16*)regA;          // overlays xl1+xr1 (dead by then)
  float* h1     = (float*)alloc((size_t)NN * 128 * sizeof(float));
  float* xr2    = (float*)alloc((size_t)NN * 256 * sizeof(float));
  float* h2     = xr2;                                   // in-place: each node reads its xr row before writing
  float* pooled = (float*)alloc((size_t)NG * 256 * sizeof(float));
  (void)ws_size; (void)in_sizes; (void)n_in; (void)out_size;

  hipMemsetAsync(deg, 0, NN * sizeof(int), stream);
  hipMemsetAsync(fill, 0, NN * sizeof(int), stream);

  const int EB = (NEP + 255) / 256;
  k_deg<<<EB, 256, 0, stream>>>(ei, deg);
  k_scan<<<1, 1024, 0, stream>>>(deg, rowptr);
  k_scatter<<<EB, 256, 0, stream>>>(ei, rowptr, fill, srcidx);

  const int RB = (NN + 63) / 64;
  // ---- layer 1 (64 -> 4x32) ----
  dim3 g1(RB, 2);
  k_gemm2<64><<<g1, 256, 0, stream>>>(x, Wl1, bl1, Wr1, br1, xl1, xr1, 128);
  k_fused<128><<<(NN + 3) / 4, 256, 0, stream>>>(rowptr, srcidx, xl1, xr1, att1, bias1, h1);

  // ---- layer 2 (128 -> 4x64) ----
  dim3 g2(RB, 4);
  k_gemm2<128><<<g2, 256, 0, stream>>>(h1, Wl2, bl2, Wr2, br2, xl2, xr2, 256);
  k_fused<256><<<(NN + 3) / 4, 256, 0, stream>>>(rowptr, srcidx, xl2, xr2, att2, bias2, h2);

  // ---- pool + classifier ----
  k_pool<<<NG, 256, 0, stream>>>(h2, batch, pooled);
  k_cls<<<NG, 128, 0, stream>>>(pooled, Wf1, bf1, Wf2, bf2, out);
}

// Round 10
// 514.593 us; speedup vs baseline: 3.9043x; 1.0971x over previous
//
#include <hip/hip_runtime.h>
#include <hip/hip_bf16.h>
#include <math.h>

#define NN 50000
#define NE 800000
#define NEP (NE + NN)   /* edges + self loops */
#define NG 128

typedef unsigned short u16;
typedef __bf16 bf16x8 __attribute__((ext_vector_type(8)));
typedef float f32x4 __attribute__((ext_vector_type(4)));

__device__ __forceinline__ float lrelu02(float v) {
  return fmaxf(v, 0.0f) + 0.2f * fminf(v, 0.0f);
}
__device__ __forceinline__ float eluf(float v) {
  return v > 0.0f ? v : expm1f(v);
}
__device__ __forceinline__ float bflo(unsigned u) {
  union { unsigned i; float f; } c; c.i = u << 16; return c.f;
}
__device__ __forceinline__ float bfhi(unsigned u) {
  union { unsigned i; float f; } c; c.i = u & 0xffff0000u; return c.f;
}
__device__ __forceinline__ bf16x8 load8(const u16* p) {
  union { uint4 u; bf16x8 v; } c;
  c.u = *(const uint4*)p;
  return c.v;
}

__global__ __launch_bounds__(256) void k_deg(const int* __restrict__ ei, int* __restrict__ deg) {
  int t = blockIdx.x * 256 + threadIdx.x;
  if (t >= NEP) return;
  int dst = (t < NE) ? ei[NE + t] : (t - NE);
  atomicAdd(&deg[dst], 1);
}

__global__ __launch_bounds__(1024) void k_scan(const int* __restrict__ deg, int* __restrict__ rowptr) {
  __shared__ int part[1024];
  int t = threadIdx.x;
  const int CH = (NN + 1023) >> 10;          // 49
  int b = t * CH;
  int e = min(b + CH, NN);
  int s = 0;
  for (int i = b; i < e; ++i) s += deg[i];
  part[t] = s;
  __syncthreads();
  for (int off = 1; off < 1024; off <<= 1) {
    int v = (t >= off) ? part[t - off] : 0;
    __syncthreads();
    part[t] += v;
    __syncthreads();
  }
  int run = (t == 0) ? 0 : part[t - 1];
  for (int i = b; i < e; ++i) { rowptr[i] = run; run += deg[i]; }
  if (t == 1023) rowptr[NN] = part[1023];
}

__global__ __launch_bounds__(256) void k_scatter(const int* __restrict__ ei, const int* __restrict__ rowptr,
                                                 int* __restrict__ fill, int* __restrict__ srcidx) {
  int t = blockIdx.x * 256 + threadIdx.x;
  if (t >= NEP) return;
  int src, dst;
  if (t < NE) { src = ei[t]; dst = ei[NE + t]; } else { src = t - NE; dst = src; }
  int pos = atomicAdd(&fill[dst], 1);
  srcidx[rowptr[dst] + pos] = src;
}

// f32 -> bf16 converters
__global__ __launch_bounds__(256) void k_cvtx(const float* __restrict__ x, u16* __restrict__ o, int n4) {
  int t = blockIdx.x * 256 + threadIdx.x;
  if (t >= n4) return;
  float4 v = ((const float4*)x)[t];
  __hip_bfloat16 b[4] = {__float2bfloat16(v.x), __float2bfloat16(v.y),
                         __float2bfloat16(v.z), __float2bfloat16(v.w)};
  ((uint2*)o)[t] = *(uint2*)b;
}

__global__ __launch_bounds__(256) void k_cvtw(const float* __restrict__ w1, const float* __restrict__ w2,
                                              const float* __restrict__ w3, const float* __restrict__ w4,
                                              u16* __restrict__ o) {
  // layout: w1@0 (8192), w2@8192 (8192), w3@16384 (32768), w4@49152 (32768)
  int t = blockIdx.x * 256 + threadIdx.x;
  if (t >= 81920) return;
  float v;
  if (t < 8192) v = w1[t];
  else if (t < 16384) v = w2[t - 8192];
  else if (t < 49152) v = w3[t - 16384];
  else v = w4[t - 49152];
  __hip_bfloat16 b = __float2bfloat16(v);
  o[t] = *(u16*)&b;
}

// ---- MFMA dual GEMM: Y = X@W^T + bias, W picked by blockIdx.z (l: bf16 out, r: f32 out)
// No LDS: A/B fragments loaded directly from L2/L3-resident bf16 tables.
// mfma_f32_16x16x32_bf16 layouts (m89-verified):
//   A: lane l, reg r -> row = l&15, k = (l>>4)*8 + r   (8 consecutive bf16 = 16B load)
//   B: lane l, reg r -> col = l&15, k = (l>>4)*8 + r
//   D: lane l, reg v -> col = l&15, row = (l>>4)*4 + v
// Wave = 16 rows x 64 cols (4 N-tiles); block = 4 waves = 64 rows x 64 cols.
template <int K>
__global__ __launch_bounds__(256) void k_mfma(const u16* __restrict__ Xb,
                                              const u16* __restrict__ Wlb, const u16* __restrict__ Wrb,
                                              const float* __restrict__ bl, const float* __restrict__ br,
                                              __hip_bfloat16* __restrict__ Yl, float* __restrict__ Yr,
                                              int dout) {
  int lane = threadIdx.x & 63;
  int wid = threadIdx.x >> 6;
  int r0 = blockIdx.x * 64 + wid * 16;
  int c0 = blockIdx.y * 64;
  bool isR = (blockIdx.z != 0);
  const u16* W = isR ? Wrb : Wlb;
  const float* bias = isR ? br : bl;

  int arow = min(r0 + (lane & 15), NN - 1);
  int koff = (lane >> 4) * 8;
  const u16* ap = Xb + (size_t)arow * K + koff;
  const u16* bp = W + (size_t)(c0 + (lane & 15)) * K + koff;

  f32x4 acc[4] = {};
#pragma unroll
  for (int ks = 0; ks < K / 32; ++ks) {
    bf16x8 a  = load8(ap + ks * 32);
    bf16x8 b0 = load8(bp + ks * 32);
    bf16x8 b1 = load8(bp + 16 * K + ks * 32);
    bf16x8 b2 = load8(bp + 32 * K + ks * 32);
    bf16x8 b3 = load8(bp + 48 * K + ks * 32);
    acc[0] = __builtin_amdgcn_mfma_f32_16x16x32_bf16(a, b0, acc[0], 0, 0, 0);
    acc[1] = __builtin_amdgcn_mfma_f32_16x16x32_bf16(a, b1, acc[1], 0, 0, 0);
    acc[2] = __builtin_amdgcn_mfma_f32_16x16x32_bf16(a, b2, acc[2], 0, 0, 0);
    acc[3] = __builtin_amdgcn_mfma_f32_16x16x32_bf16(a, b3, acc[3], 0, 0, 0);
  }

  int orow = r0 + ((lane >> 4) << 2);
  int ocol = c0 + (lane & 15);
#pragma unroll
  for (int t = 0; t < 4; ++t) {
    int col = ocol + t * 16;
    float bv = bias[col];
    if (!isR) {
#pragma unroll
      for (int v = 0; v < 4; ++v) {
        int row = orow + v;
        if (row < NN) Yl[(size_t)row * dout + col] = __float2bfloat16(acc[t][v] + bv);
      }
    } else {
#pragma unroll
      for (int v = 0; v < 4; ++v) {
        int row = orow + v;
        if (row < NN) Yr[(size_t)row * dout + col] = acc[t][v] + bv;
      }
    }
  }
}

// ---- fused GATv2 edge-score + softmax + aggregation ----
// wave per dst node; lane l owns channels [l*V, l*V+V); 16 lanes per head.
// Softmax with fixed shift m=0 (scores ~ +-6, shift-invariant => identical math).
// xl gathered in bf16; optional bf16 output (feeds layer-2 MFMA directly).
template <int D, bool OBF16>
__global__ __launch_bounds__(256) void k_fused(const int* __restrict__ rowptr, const int* __restrict__ srcidx,
                                               const __hip_bfloat16* __restrict__ xl, const float* __restrict__ xr,
                                               const float* __restrict__ att, const float* __restrict__ bias,
                                               void* __restrict__ outv) {
  constexpr int V = D / 64;   // 2 (layer1) or 4 (layer2)
  int lane = threadIdx.x & 63;
  int node = blockIdx.x * 4 + (threadIdx.x >> 6);
  if (node >= NN) return;
  int lo = rowptr[node], hi = rowptr[node + 1];

  float xrv[V], attv[V];
#pragma unroll
  for (int q = 0; q < V; ++q) {
    xrv[q]  = xr[(size_t)node * D + lane * V + q];
    attv[q] = att[lane * V + q];
  }

  const unsigned* xl1 = (const unsigned*)xl;   // V==2: one dword per lane
  const uint2*    xl2 = (const uint2*)xl;      // V==4: 8B per lane

  float denom = 0.f;
  float acc[V] = {};

  auto gather = [&](int j, float* xv) {
    if constexpr (V == 2) {
      unsigned u = xl1[(size_t)j * (D / 2) + lane];
      xv[0] = bflo(u); xv[1] = bfhi(u);
    } else {
      uint2 u = xl2[(size_t)j * (D / 4) + lane];
      xv[0] = bflo(u.x); xv[1] = bfhi(u.x);
      xv[2] = bflo(u.y); xv[3] = bfhi(u.y);
    }
  };
  auto score_partial = [&](const float* xv) {
    float p = 0.f;
#pragma unroll
    for (int q = 0; q < V; ++q) p += attv[q] * lrelu02(xv[q] + xrv[q]);
    return p;
  };
  auto update = [&](float sh, const float* xv) {
    float w = __expf(sh);
    denom += w;
#pragma unroll
    for (int q = 0; q < V; ++q) acc[q] += w * xv[q];
  };

  int s = lo;
  for (; s + 3 < hi; s += 4) {
    int j0 = srcidx[s], j1 = srcidx[s + 1], j2 = srcidx[s + 2], j3 = srcidx[s + 3];
    float xv0[V], xv1[V], xv2[V], xv3[V];
    gather(j0, xv0); gather(j1, xv1); gather(j2, xv2); gather(j3, xv3);
    float p0 = score_partial(xv0);
    float p1 = score_partial(xv1);
    float p2 = score_partial(xv2);
    float p3 = score_partial(xv3);
#pragma unroll
    for (int off = 1; off < 16; off <<= 1) {
      p0 += __shfl_xor(p0, off);
      p1 += __shfl_xor(p1, off);
      p2 += __shfl_xor(p2, off);
      p3 += __shfl_xor(p3, off);
    }
    update(p0, xv0); update(p1, xv1); update(p2, xv2); update(p3, xv3);
  }
  for (; s < hi; ++s) {
    int j0 = srcidx[s];
    float xv0[V];
    gather(j0, xv0);
    float p0 = score_partial(xv0);
#pragma unroll
    for (int off = 1; off < 16; off <<= 1) p0 += __shfl_xor(p0, off);
    update(p0, xv0);
  }

  float rd = 1.0f / denom;
  float vals[V];
#pragma unroll
  for (int q = 0; q < V; ++q) vals[q] = eluf(acc[q] * rd + bias[lane * V + q]);

  if constexpr (OBF16) {
    __hip_bfloat16 tmp[V];
#pragma unroll
    for (int q = 0; q < V; ++q) tmp[q] = __float2bfloat16(vals[q]);
    if constexpr (V == 2) ((unsigned*)outv)[(size_t)node * (D / 2) + lane] = *(unsigned*)tmp;
    else                  ((uint2*)outv)[(size_t)node * (D / 4) + lane] = *(uint2*)tmp;
  } else {
    float* out = (float*)outv;
#pragma unroll
    for (int q = 0; q < V; ++q) out[(size_t)node * D + lane * V + q] = vals[q];
  }
}

__device__ __forceinline__ int lowerb(const int* __restrict__ a, int n, int v) {
  int lo = 0, hi = n;
  while (lo < hi) { int mid = (lo + hi) >> 1; if (a[mid] < v) lo = mid + 1; else hi = mid; }
  return lo;
}

__global__ __launch_bounds__(256) void k_pool(const float* __restrict__ h2, const int* __restrict__ batch,
                                              float* __restrict__ pooled) {
  int g = blockIdx.x, t = threadIdx.x;
  int lo = lowerb(batch, NN, g);
  int hi = lowerb(batch, NN, g + 1);
  float acc = 0.f;
  for (int n = lo; n < hi; ++n) acc += h2[(size_t)n * 256 + t];
  float cnt = (float)(hi - lo);
  pooled[g * 256 + t] = acc / fmaxf(cnt, 1.0f);
}

__global__ __launch_bounds__(128) void k_cls(const float* __restrict__ pooled, const float* __restrict__ Wf1,
                                             const float* __restrict__ bf1, const float* __restrict__ Wf2,
                                             const float* __restrict__ bf2, float* __restrict__ out) {
  __shared__ float p[256];
  __shared__ float z[128];
  int g = blockIdx.x, t = threadIdx.x;
  p[t] = pooled[g * 256 + t];
  p[t + 128] = pooled[g * 256 + t + 128];
  __syncthreads();
  float a = bf1[t];
  const float* wr = Wf1 + (size_t)t * 256;
  for (int k = 0; k < 256; ++k) a += p[k] * wr[k];
  z[t] = fmaxf(a, 0.f);
  __syncthreads();
  if (t < 8) {
    float o = bf2[t];
    const float* w2 = Wf2 + t * 128;
    for (int k = 0; k < 128; ++k) o += z[k] * w2[k];
    out[g * 8 + t] = o;
  }
}

extern "C" void kernel_launch(void* const* d_in, const int* in_sizes, int n_in,
                              void* d_out, int out_size, void* d_ws, size_t ws_size,
                              hipStream_t stream) {
  const float* x     = (const float*)d_in[0];
  const int*   ei    = (const int*)d_in[1];
  const int*   batch = (const int*)d_in[2];
  const float* Wl1 = (const float*)d_in[3];
  const float* bl1 = (const float*)d_in[4];
  const float* Wr1 = (const float*)d_in[5];
  const float* br1 = (const float*)d_in[6];
  const float* att1  = (const float*)d_in[7];
  const float* bias1 = (const float*)d_in[8];
  const float* Wl2 = (const float*)d_in[9];
  const float* bl2 = (const float*)d_in[10];
  const float* Wr2 = (const float*)d_in[11];
  const float* br2 = (const float*)d_in[12];
  const float* att2  = (const float*)d_in[13];
  const float* bias2 = (const float*)d_in[14];
  const float* Wf1 = (const float*)d_in[15];
  const float* bf1 = (const float*)d_in[16];
  const float* Wf2 = (const float*)d_in[17];
  const float* bf2 = (const float*)d_in[18];
  float* out = (float*)d_out;

  char* w = (char*)d_ws;
  size_t off = 0;
  auto alloc = [&](size_t bytes) -> void* {
    void* p = w + off;
    off += (bytes + 255) & ~(size_t)255;
    return p;
  };
  int* rowptr = (int*)alloc((NN + 1) * sizeof(int));
  int* deg    = (int*)alloc(NN * sizeof(int));
  int* fill   = (int*)alloc(NN * sizeof(int));
  int* srcidx = (int*)alloc((size_t)NEP * sizeof(int));
  u16* Xb1    = (u16*)alloc((size_t)NN * 64 * sizeof(u16));     // x in bf16
  u16* Wb     = (u16*)alloc((size_t)81920 * sizeof(u16));       // all 4 W in bf16
  u16* Wl1b = Wb, *Wr1b = Wb + 8192, *Wl2b = Wb + 16384, *Wr2b = Wb + 49152;
  // region A: xl1(bf16 12.8MB) + xr1(f32 25.6MB), later reused for xl2(bf16 25.6MB)
  char* regA  = (char*)alloc((size_t)NN * 128 * 2 + (size_t)NN * 128 * 4);
  __hip_bfloat16* xl1 = (__hip_bfloat16*)regA;
  float*          xr1 = (float*)(regA + (size_t)NN * 128 * 2);
  __hip_bfloat16* xl2 = (__hip_bfloat16*)regA;          // overlays xl1+xr1 (dead by then)
  u16*   h1b    = (u16*)alloc((size_t)NN * 128 * sizeof(u16)); // h1 in bf16 (layer-2 A)
  float* xr2    = (float*)alloc((size_t)NN * 256 * sizeof(float));
  float* h2     = xr2;   // in-place: each node reads its xr row before writing
  float* pooled = (float*)alloc((size_t)NG * 256 * sizeof(float));
  (void)ws_size; (void)in_sizes; (void)n_in; (void)out_size;

  hipMemsetAsync(deg, 0, NN * sizeof(int), stream);
  hipMemsetAsync(fill, 0, NN * sizeof(int), stream);

  const int EB = (NEP + 255) / 256;
  k_deg<<<EB, 256, 0, stream>>>(ei, deg);
  k_scan<<<1, 1024, 0, stream>>>(deg, rowptr);
  k_scatter<<<EB, 256, 0, stream>>>(ei, rowptr, fill, srcidx);

  // bf16 conversions
  k_cvtx<<<(NN * 64 / 4 + 255) / 256, 256, 0, stream>>>(x, Xb1, NN * 64 / 4);
  k_cvtw<<<(81920 + 255) / 256, 256, 0, stream>>>(Wl1, Wr1, Wl2, Wr2, Wb);

  const int RB = (NN + 63) / 64;
  // ---- layer 1 (64 -> 4x32) ----
  dim3 g1(RB, 2, 2);
  k_mfma<64><<<g1, 256, 0, stream>>>(Xb1, Wl1b, Wr1b, bl1, br1, xl1, xr1, 128);
  k_fused<128, true><<<(NN + 3) / 4, 256, 0, stream>>>(rowptr, srcidx, xl1, xr1, att1, bias1, h1b);

  // ---- layer 2 (128 -> 4x64) ----
  dim3 g2(RB, 4, 2);
  k_mfma<128><<<g2, 256, 0, stream>>>(h1b, Wl2b, Wr2b, bl2, br2, xl2, xr2, 256);
  k_fused<256, false><<<(NN + 3) / 4, 256, 0, stream>>>(rowptr, srcidx, xl2, xr2, att2, bias2, h2);

  // ---- pool + classifier ----
  k_pool<<<NG, 256, 0, stream>>>(h2, batch, pooled);
  k_cls<<<NG, 128, 0, stream>>>(pooled, Wf1, bf1, Wf2, bf2, out);
}

// Round 11
// 421.572 us; speedup vs baseline: 4.7658x; 1.2207x over previous
//
#include <hip/hip_runtime.h>
#include <hip/hip_bf16.h>
#include <math.h>

#define NN 50000
#define NE 800000
#define NEP (NE + NN)   /* edges + self loops */
#define NG 128
#define PSPLIT 16

typedef unsigned short u16;
typedef __bf16 bf16x8 __attribute__((ext_vector_type(8)));
typedef float f32x4 __attribute__((ext_vector_type(4)));

__device__ __forceinline__ float lrelu02(float v) {
  return fmaxf(v, 0.0f) + 0.2f * fminf(v, 0.0f);
}
__device__ __forceinline__ float eluf(float v) {
  return v > 0.0f ? v : expm1f(v);
}
__device__ __forceinline__ float bflo(unsigned u) {
  union { unsigned i; float f; } c; c.i = u << 16; return c.f;
}
__device__ __forceinline__ float bfhi(unsigned u) {
  union { unsigned i; float f; } c; c.i = u & 0xffff0000u; return c.f;
}
__device__ __forceinline__ bf16x8 load8(const u16* p) {
  union { uint4 u; bf16x8 v; } c;
  c.u = *(const uint4*)p;
  return c.v;
}

__global__ __launch_bounds__(256) void k_deg(const int* __restrict__ ei, int* __restrict__ deg) {
  int t = blockIdx.x * 256 + threadIdx.x;
  if (t >= NEP) return;
  int dst = (t < NE) ? ei[NE + t] : (t - NE);
  atomicAdd(&deg[dst], 1);
}

__global__ __launch_bounds__(1024) void k_scan(const int* __restrict__ deg, int* __restrict__ rowptr) {
  __shared__ int part[1024];
  int t = threadIdx.x;
  const int CH = (NN + 1023) >> 10;          // 49
  int b = t * CH;
  int e = min(b + CH, NN);
  int s = 0;
  for (int i = b; i < e; ++i) s += deg[i];
  part[t] = s;
  __syncthreads();
  for (int off = 1; off < 1024; off <<= 1) {
    int v = (t >= off) ? part[t - off] : 0;
    __syncthreads();
    part[t] += v;
    __syncthreads();
  }
  int run = (t == 0) ? 0 : part[t - 1];
  for (int i = b; i < e; ++i) { rowptr[i] = run; run += deg[i]; }
  if (t == 1023) rowptr[NN] = part[1023];
}

__global__ __launch_bounds__(256) void k_scatter(const int* __restrict__ ei, const int* __restrict__ rowptr,
                                                 int* __restrict__ fill, int* __restrict__ srcidx) {
  int t = blockIdx.x * 256 + threadIdx.x;
  if (t >= NEP) return;
  int src, dst;
  if (t < NE) { src = ei[t]; dst = ei[NE + t]; } else { src = t - NE; dst = src; }
  int pos = atomicAdd(&fill[dst], 1);
  srcidx[rowptr[dst] + pos] = src;
}

// f32 -> bf16 converters
__global__ __launch_bounds__(256) void k_cvtx(const float* __restrict__ x, u16* __restrict__ o, int n4) {
  int t = blockIdx.x * 256 + threadIdx.x;
  if (t >= n4) return;
  float4 v = ((const float4*)x)[t];
  __hip_bfloat16 b[4] = {__float2bfloat16(v.x), __float2bfloat16(v.y),
                         __float2bfloat16(v.z), __float2bfloat16(v.w)};
  ((uint2*)o)[t] = *(uint2*)b;
}

__global__ __launch_bounds__(256) void k_cvtw(const float* __restrict__ w1, const float* __restrict__ w2,
                                              const float* __restrict__ w3, const float* __restrict__ w4,
                                              u16* __restrict__ o) {
  // layout: w1@0 (8192), w2@8192 (8192), w3@16384 (32768), w4@49152 (32768)
  int t = blockIdx.x * 256 + threadIdx.x;
  if (t >= 81920) return;
  float v;
  if (t < 8192) v = w1[t];
  else if (t < 16384) v = w2[t - 8192];
  else if (t < 49152) v = w3[t - 16384];
  else v = w4[t - 49152];
  __hip_bfloat16 b = __float2bfloat16(v);
  o[t] = *(u16*)&b;
}

// ---- MFMA dual GEMM: Y = X@W^T + bias, W picked by blockIdx.z (l: bf16 out, r: f32 out)
// No LDS: A/B fragments loaded directly from L2/L3-resident bf16 tables.
// mfma_f32_16x16x32_bf16 layouts (m89-verified):
//   A: lane l, reg r -> row = l&15, k = (l>>4)*8 + r   (8 consecutive bf16 = 16B load)
//   B: lane l, reg r -> col = l&15, k = (l>>4)*8 + r
//   D: lane l, reg v -> col = l&15, row = (l>>4)*4 + v
// Wave = 16 rows x 64 cols (4 N-tiles); block = 4 waves = 64 rows x 64 cols.
template <int K>
__global__ __launch_bounds__(256) void k_mfma(const u16* __restrict__ Xb,
                                              const u16* __restrict__ Wlb, const u16* __restrict__ Wrb,
                                              const float* __restrict__ bl, const float* __restrict__ br,
                                              __hip_bfloat16* __restrict__ Yl, float* __restrict__ Yr,
                                              int dout) {
  int lane = threadIdx.x & 63;
  int wid = threadIdx.x >> 6;
  int r0 = blockIdx.x * 64 + wid * 16;
  int c0 = blockIdx.y * 64;
  bool isR = (blockIdx.z != 0);
  const u16* W = isR ? Wrb : Wlb;
  const float* bias = isR ? br : bl;

  int arow = min(r0 + (lane & 15), NN - 1);
  int koff = (lane >> 4) * 8;
  const u16* ap = Xb + (size_t)arow * K + koff;
  const u16* bp = W + (size_t)(c0 + (lane & 15)) * K + koff;

  f32x4 acc[4] = {};
#pragma unroll
  for (int ks = 0; ks < K / 32; ++ks) {
    bf16x8 a  = load8(ap + ks * 32);
    bf16x8 b0 = load8(bp + ks * 32);
    bf16x8 b1 = load8(bp + 16 * K + ks * 32);
    bf16x8 b2 = load8(bp + 32 * K + ks * 32);
    bf16x8 b3 = load8(bp + 48 * K + ks * 32);
    acc[0] = __builtin_amdgcn_mfma_f32_16x16x32_bf16(a, b0, acc[0], 0, 0, 0);
    acc[1] = __builtin_amdgcn_mfma_f32_16x16x32_bf16(a, b1, acc[1], 0, 0, 0);
    acc[2] = __builtin_amdgcn_mfma_f32_16x16x32_bf16(a, b2, acc[2], 0, 0, 0);
    acc[3] = __builtin_amdgcn_mfma_f32_16x16x32_bf16(a, b3, acc[3], 0, 0, 0);
  }

  int orow = r0 + ((lane >> 4) << 2);
  int ocol = c0 + (lane & 15);
#pragma unroll
  for (int t = 0; t < 4; ++t) {
    int col = ocol + t * 16;
    float bv = bias[col];
    if (!isR) {
#pragma unroll
      for (int v = 0; v < 4; ++v) {
        int row = orow + v;
        if (row < NN) Yl[(size_t)row * dout + col] = __float2bfloat16(acc[t][v] + bv);
      }
    } else {
#pragma unroll
      for (int v = 0; v < 4; ++v) {
        int row = orow + v;
        if (row < NN) Yr[(size_t)row * dout + col] = acc[t][v] + bv;
      }
    }
  }
}

// ---- fused GATv2 edge-score + softmax + aggregation ----
// wave per dst node; lane l owns channels [l*V, l*V+V); 16 lanes per head.
// Softmax with fixed shift m=0 (scores ~ +-6, shift-invariant => identical math).
// xl gathered in bf16; optional bf16 output (feeds layer-2 MFMA directly).
template <int D, bool OBF16>
__global__ __launch_bounds__(256) void k_fused(const int* __restrict__ rowptr, const int* __restrict__ srcidx,
                                               const __hip_bfloat16* __restrict__ xl, const float* __restrict__ xr,
                                               const float* __restrict__ att, const float* __restrict__ bias,
                                               void* __restrict__ outv) {
  constexpr int V = D / 64;   // 2 (layer1) or 4 (layer2)
  int lane = threadIdx.x & 63;
  int node = blockIdx.x * 4 + (threadIdx.x >> 6);
  if (node >= NN) return;
  int lo = rowptr[node], hi = rowptr[node + 1];

  float xrv[V], attv[V];
#pragma unroll
  for (int q = 0; q < V; ++q) {
    xrv[q]  = xr[(size_t)node * D + lane * V + q];
    attv[q] = att[lane * V + q];
  }

  const unsigned* xl1 = (const unsigned*)xl;   // V==2: one dword per lane
  const uint2*    xl2 = (const uint2*)xl;      // V==4: 8B per lane

  float denom = 0.f;
  float acc[V] = {};

  auto gather = [&](int j, float* xv) {
    if constexpr (V == 2) {
      unsigned u = xl1[(size_t)j * (D / 2) + lane];
      xv[0] = bflo(u); xv[1] = bfhi(u);
    } else {
      uint2 u = xl2[(size_t)j * (D / 4) + lane];
      xv[0] = bflo(u.x); xv[1] = bfhi(u.x);
      xv[2] = bflo(u.y); xv[3] = bfhi(u.y);
    }
  };
  auto score_partial = [&](const float* xv) {
    float p = 0.f;
#pragma unroll
    for (int q = 0; q < V; ++q) p += attv[q] * lrelu02(xv[q] + xrv[q]);
    return p;
  };
  auto update = [&](float sh, const float* xv) {
    float w = __expf(sh);
    denom += w;
#pragma unroll
    for (int q = 0; q < V; ++q) acc[q] += w * xv[q];
  };

  int s = lo;
  for (; s + 3 < hi; s += 4) {
    int j0 = srcidx[s], j1 = srcidx[s + 1], j2 = srcidx[s + 2], j3 = srcidx[s + 3];
    float xv0[V], xv1[V], xv2[V], xv3[V];
    gather(j0, xv0); gather(j1, xv1); gather(j2, xv2); gather(j3, xv3);
    float p0 = score_partial(xv0);
    float p1 = score_partial(xv1);
    float p2 = score_partial(xv2);
    float p3 = score_partial(xv3);
#pragma unroll
    for (int off = 1; off < 16; off <<= 1) {
      p0 += __shfl_xor(p0, off);
      p1 += __shfl_xor(p1, off);
      p2 += __shfl_xor(p2, off);
      p3 += __shfl_xor(p3, off);
    }
    update(p0, xv0); update(p1, xv1); update(p2, xv2); update(p3, xv3);
  }
  for (; s < hi; ++s) {
    int j0 = srcidx[s];
    float xv0[V];
    gather(j0, xv0);
    float p0 = score_partial(xv0);
#pragma unroll
    for (int off = 1; off < 16; off <<= 1) p0 += __shfl_xor(p0, off);
    update(p0, xv0);
  }

  float rd = 1.0f / denom;
  float vals[V];
#pragma unroll
  for (int q = 0; q < V; ++q) vals[q] = eluf(acc[q] * rd + bias[lane * V + q]);

  if constexpr (OBF16) {
    __hip_bfloat16 tmp[V];
#pragma unroll
    for (int q = 0; q < V; ++q) tmp[q] = __float2bfloat16(vals[q]);
    if constexpr (V == 2) ((unsigned*)outv)[(size_t)node * (D / 2) + lane] = *(unsigned*)tmp;
    else                  ((uint2*)outv)[(size_t)node * (D / 4) + lane] = *(uint2*)tmp;
  } else {
    float* out = (float*)outv;
#pragma unroll
    for (int q = 0; q < V; ++q) out[(size_t)node * D + lane * V + q] = vals[q];
  }
}

__device__ __forceinline__ int lowerb(const int* __restrict__ a, int n, int v) {
  int lo = 0, hi = n;
  while (lo < hi) { int mid = (lo + hi) >> 1; if (a[mid] < v) lo = mid + 1; else hi = mid; }
  return lo;
}

// ---- two-stage mean pool ----
// stage 1: grid (NG, PSPLIT); each block sums a node chunk of graph g into a
// partial buffer (no atomics -> deterministic). 2048 blocks -> latency hidden.
__global__ __launch_bounds__(256) void k_pool(const float* __restrict__ h2, const int* __restrict__ batch,
                                              float* __restrict__ pooled_p) {
  int g = blockIdx.x, sp = blockIdx.y, t = threadIdx.x;
  __shared__ int sh[2];
  if (t < 2) sh[t] = lowerb(batch, NN, g + t);
  __syncthreads();
  int lo = sh[0], hi = sh[1];
  int cnt = hi - lo;
  int chunk = (cnt + PSPLIT - 1) / PSPLIT;
  int b = lo + sp * chunk;
  int e = min(b + chunk, hi);
  float acc = 0.f;
  for (int n = b; n < e; ++n) acc += h2[(size_t)n * 256 + t];
  pooled_p[((size_t)g * PSPLIT + sp) * 256 + t] = acc;
}

// stage 2 + classifier: reduce partials, mean, Linear->ReLU->Linear
__global__ __launch_bounds__(128) void k_cls(const float* __restrict__ pooled_p, const int* __restrict__ batch,
                                             const float* __restrict__ Wf1, const float* __restrict__ bf1,
                                             const float* __restrict__ Wf2, const float* __restrict__ bf2,
                                             float* __restrict__ out) {
  __shared__ float p[256];
  __shared__ float z[128];
  __shared__ int sh[2];
  int g = blockIdx.x, t = threadIdx.x;
  if (t < 2) sh[t] = lowerb(batch, NN, g + t);
  __syncthreads();
  float cnt = (float)(sh[1] - sh[0]);
  float rinv = 1.0f / fmaxf(cnt, 1.0f);
  const float* pp = pooled_p + (size_t)g * PSPLIT * 256;
#pragma unroll 1
  for (int c = t; c < 256; c += 128) {
    float s = 0.f;
#pragma unroll
    for (int sp = 0; sp < PSPLIT; ++sp) s += pp[sp * 256 + c];
    p[c] = s * rinv;
  }
  __syncthreads();
  float a = bf1[t];
  const float* wr = Wf1 + (size_t)t * 256;
  for (int k = 0; k < 256; ++k) a += p[k] * wr[k];
  z[t] = fmaxf(a, 0.f);
  __syncthreads();
  if (t < 8) {
    float o = bf2[t];
    const float* w2 = Wf2 + t * 128;
    for (int k = 0; k < 128; ++k) o += z[k] * w2[k];
    out[g * 8 + t] = o;
  }
}

extern "C" void kernel_launch(void* const* d_in, const int* in_sizes, int n_in,
                              void* d_out, int out_size, void* d_ws, size_t ws_size,
                              hipStream_t stream) {
  const float* x     = (const float*)d_in[0];
  const int*   ei    = (const int*)d_in[1];
  const int*   batch = (const int*)d_in[2];
  const float* Wl1 = (const float*)d_in[3];
  const float* bl1 = (const float*)d_in[4];
  const float* Wr1 = (const float*)d_in[5];
  const float* br1 = (const float*)d_in[6];
  const float* att1  = (const float*)d_in[7];
  const float* bias1 = (const float*)d_in[8];
  const float* Wl2 = (const float*)d_in[9];
  const float* bl2 = (const float*)d_in[10];
  const float* Wr2 = (const float*)d_in[11];
  const float* br2 = (const float*)d_in[12];
  const float* att2  = (const float*)d_in[13];
  const float* bias2 = (const float*)d_in[14];
  const float* Wf1 = (const float*)d_in[15];
  const float* bf1 = (const float*)d_in[16];
  const float* Wf2 = (const float*)d_in[17];
  const float* bf2 = (const float*)d_in[18];
  float* out = (float*)d_out;

  char* w = (char*)d_ws;
  size_t off = 0;
  auto alloc = [&](size_t bytes) -> void* {
    void* p = w + off;
    off += (bytes + 255) & ~(size_t)255;
    return p;
  };
  int* rowptr = (int*)alloc((NN + 1) * sizeof(int));
  int* deg    = (int*)alloc(NN * sizeof(int));
  int* fill   = (int*)alloc(NN * sizeof(int));
  int* srcidx = (int*)alloc((size_t)NEP * sizeof(int));
  u16* Xb1    = (u16*)alloc((size_t)NN * 64 * sizeof(u16));     // x in bf16
  u16* Wb     = (u16*)alloc((size_t)81920 * sizeof(u16));       // all 4 W in bf16
  u16* Wl1b = Wb, *Wr1b = Wb + 8192, *Wl2b = Wb + 16384, *Wr2b = Wb + 49152;
  // region A: xl1(bf16 12.8MB) + xr1(f32 25.6MB), later reused for xl2(bf16 25.6MB)
  char* regA  = (char*)alloc((size_t)NN * 128 * 2 + (size_t)NN * 128 * 4);
  __hip_bfloat16* xl1 = (__hip_bfloat16*)regA;
  float*          xr1 = (float*)(regA + (size_t)NN * 128 * 2);
  __hip_bfloat16* xl2 = (__hip_bfloat16*)regA;          // overlays xl1+xr1 (dead by then)
  u16*   h1b    = (u16*)alloc((size_t)NN * 128 * sizeof(u16)); // h1 in bf16 (layer-2 A)
  float* xr2    = (float*)alloc((size_t)NN * 256 * sizeof(float));
  float* h2     = xr2;   // in-place: each node reads its xr row before writing
  float* pooled_p = (float*)alloc((size_t)NG * PSPLIT * 256 * sizeof(float));
  (void)ws_size; (void)in_sizes; (void)n_in; (void)out_size;

  hipMemsetAsync(deg, 0, NN * sizeof(int), stream);
  hipMemsetAsync(fill, 0, NN * sizeof(int), stream);

  const int EB = (NEP + 255) / 256;
  k_deg<<<EB, 256, 0, stream>>>(ei, deg);
  k_scan<<<1, 1024, 0, stream>>>(deg, rowptr);
  k_scatter<<<EB, 256, 0, stream>>>(ei, rowptr, fill, srcidx);

  // bf16 conversions
  k_cvtx<<<(NN * 64 / 4 + 255) / 256, 256, 0, stream>>>(x, Xb1, NN * 64 / 4);
  k_cvtw<<<(81920 + 255) / 256, 256, 0, stream>>>(Wl1, Wr1, Wl2, Wr2, Wb);

  const int RB = (NN + 63) / 64;
  // ---- layer 1 (64 -> 4x32) ----
  dim3 g1(RB, 2, 2);
  k_mfma<64><<<g1, 256, 0, stream>>>(Xb1, Wl1b, Wr1b, bl1, br1, xl1, xr1, 128);
  k_fused<128, true><<<(NN + 3) / 4, 256, 0, stream>>>(rowptr, srcidx, xl1, xr1, att1, bias1, h1b);

  // ---- layer 2 (128 -> 4x64) ----
  dim3 g2(RB, 4, 2);
  k_mfma<128><<<g2, 256, 0, stream>>>(h1b, Wl2b, Wr2b, bl2, br2, xl2, xr2, 256);
  k_fused<256, false><<<(NN + 3) / 4, 256, 0, stream>>>(rowptr, srcidx, xl2, xr2, att2, bias2, h2);

  // ---- pool + classifier ----
  dim3 gp(NG, PSPLIT);
  k_pool<<<gp, 256, 0, stream>>>(h2, batch, pooled_p);
  k_cls<<<NG, 128, 0, stream>>>(pooled_p, batch, Wf1, bf1, Wf2, bf2, out);
}